// Round 11
// baseline (355.407 us; speedup 1.0000x reference)
//
#include <hip/hip_runtime.h>
#include <hip/hip_bf16.h>
#include <math.h>

#define D_IN 128
#define D_HID 128
#define D_OUT 64
#define BN_EPS 1e-5f
#define SLOPE 0.01f
#define NSCALE 1.8f

#define BSH 8          // nodes per bucket = 256
#define NB 256
#define T1 4096        // edges per partition tile
#define COLCAP 8192
#define LSTRIDE 192    // bytes per l_ext row: 64 bf16 l' + f32 s @128

typedef __attribute__((ext_vector_type(8))) short short8;
typedef __attribute__((ext_vector_type(4))) float f32x4;

__device__ inline void atomAddF(float* p, float v) {
#if defined(__gfx90a__) || defined(__gfx942__) || defined(__gfx950__)
    unsafeAtomicAdd(p, v);
#else
    atomicAdd(p, v);
#endif
}

__device__ inline ushort f2bf(float f) {  // RNE
    union { float f; uint u; } v; v.f = f;
    uint r = v.u + 0x7fff + ((v.u >> 16) & 1);
    return (ushort)(r >> 16);
}
__device__ inline float bf2f(ushort b) {
    union { uint u; float f; } v; v.u = ((uint)b) << 16;
    return v.f;
}
__device__ inline float bflo(uint u) { return __uint_as_float(u << 16); }
__device__ inline float bfhi(uint u) { return __uint_as_float(u & 0xffff0000u); }

__device__ inline void add4(uint2 v, float a[4]) {
    a[0] += bflo(v.x); a[1] += bfhi(v.x);
    a[2] += bflo(v.y); a[3] += bfhi(v.y);
}
__device__ inline void fma4(uint2 v, float w, float a[4]) {
    a[0] = fmaf(bflo(v.x), w, a[0]);
    a[1] = fmaf(bfhi(v.x), w, a[1]);
    a[2] = fmaf(bflo(v.y), w, a[2]);
    a[3] = fmaf(bfhi(v.y), w, a[3]);
}
// dual: am += v*w ; al += v*sv*w
__device__ inline void dacc4(uint2 v, float sv, float w, float am[4], float al[4]) {
    float e;
    e = bflo(v.x) * w; am[0] += e; al[0] = fmaf(e, sv, al[0]);
    e = bfhi(v.x) * w; am[1] += e; al[1] = fmaf(e, sv, al[1]);
    e = bflo(v.y) * w; am[2] += e; al[2] = fmaf(e, sv, al[2]);
    e = bfhi(v.y) * w; am[3] += e; al[3] = fmaf(e, sv, al[3]);
}

// ---- bucket histogram (LDS-staged) -------------------------------------
__global__ __launch_bounds__(256) void k_bhist(const int* __restrict__ dst,
        int* __restrict__ bcnt, int E, int B) {
    __shared__ int h[512];
    for (int i = threadIdx.x; i < 512; i += 256) h[i] = 0;
    __syncthreads();
    int beg = blockIdx.x * T1;
    int end = min(beg + T1, E);
    for (int e = beg + threadIdx.x; e < end; e += 256)
        atomicAdd(&h[dst[e] >> BSH], 1);
    __syncthreads();
    for (int i = threadIdx.x; i < B; i += 256)
        if (h[i]) atomicAdd(&bcnt[i], h[i]);
}

// ---- bucket base scan (single block, B <= 512) -------------------------
__global__ __launch_bounds__(512) void k_bscan(const int* __restrict__ bcnt,
        int* __restrict__ bbase, int* __restrict__ tailE, int B) {
    __shared__ int sh[512];
    int t = threadIdx.x;
    int v = (t < B) ? bcnt[t] : 0;
    sh[t] = v;
    __syncthreads();
    for (int o = 1; o < 512; o <<= 1) {
        int u = (t >= o) ? sh[t - o] : 0;
        __syncthreads();
        sh[t] += u;
        __syncthreads();
    }
    int excl = sh[t] - v;
    if (t < B) { bbase[t] = excl; tailE[t] = excl; }
    if (t == B - 1) bbase[B] = excl + v;
}

// ---- partition edges into bucket regions; ep packed: src | dlocal<<24 --
__global__ __launch_bounds__(256) void k_part(const int* __restrict__ src,
        const int* __restrict__ dst, int* __restrict__ tailE,
        uint* __restrict__ ep, int E, int B) {
    __shared__ int h[512], off[512], gb[512], cur[512];
    __shared__ int ps[256];
    __shared__ int2 ro[T1];
    int tid = threadIdx.x;
    for (int i = tid; i < 512; i += 256) h[i] = 0;
    __syncthreads();
    int beg = blockIdx.x * T1;
    int cnt = min(T1, E - beg);
    int s[16], d[16];
#pragma unroll
    for (int k = 0; k < 16; ++k) {
        int e = beg + tid + k * 256;
        if (e < E) {
            s[k] = src[e]; d[k] = dst[e];
            atomicAdd(&h[d[k] >> BSH], 1);
        } else d[k] = -1;
    }
    __syncthreads();
    int pa = h[2 * tid], pb = h[2 * tid + 1];
    ps[tid] = pa + pb;
    __syncthreads();
    int vv = ps[tid];
    for (int o = 1; o < 256; o <<= 1) {
        int u = (tid >= o) ? ps[tid - o] : 0;
        __syncthreads();
        ps[tid] += u;
        __syncthreads();
    }
    int excl = ps[tid] - vv;
    off[2 * tid] = excl;       off[2 * tid + 1] = excl + pa;
    cur[2 * tid] = excl;       cur[2 * tid + 1] = excl + pa;
    if (2 * tid < B && pa > 0)      gb[2 * tid] = atomicAdd(&tailE[2 * tid], pa);
    if (2 * tid + 1 < B && pb > 0)  gb[2 * tid + 1] = atomicAdd(&tailE[2 * tid + 1], pb);
    __syncthreads();
#pragma unroll
    for (int k = 0; k < 16; ++k) {
        if (d[k] >= 0) {
            int b = d[k] >> BSH;
            int p = atomicAdd(&cur[b], 1);
            ro[p] = make_int2(s[k], d[k]);
        }
    }
    __syncthreads();
    for (int i = tid; i < cnt; i += 256) {
        int2 e = ro[i];
        int b = e.y >> BSH;
        ep[gb[b] + (i - off[b])] = (uint)e.x | ((uint)(e.y & (NB - 1)) << 24);
    }
}

// ---- per-bucket: deg/rowptr/dinv + CSR col build in LDS ----------------
__global__ __launch_bounds__(256) void k_csr(const uint* __restrict__ ep,
        const int* __restrict__ bbase, int* __restrict__ rowptr,
        float* __restrict__ dinv, int* __restrict__ col, int n, int B) {
    int b = blockIdx.x;
    int lo = b << BSH;
    int hi = min(lo + NB, n);
    int nn = hi - lo;
    int ebeg = bbase[b], eend = bbase[b + 1], cnt = eend - ebeg;
    __shared__ int h[NB], pfx[NB], cur[NB];
    __shared__ int colbuf[COLCAP];
    int tid = threadIdx.x;
    if (tid < NB) h[tid] = 0;
    __syncthreads();
    for (int i = tid; i < cnt; i += 256)
        atomicAdd(&h[ep[ebeg + i] >> 24], 1);
    __syncthreads();
    int v = (tid < nn) ? h[tid] : 0;
    pfx[tid] = v;
    __syncthreads();
    for (int o = 1; o < 256; o <<= 1) {
        int u = (tid >= o) ? pfx[tid - o] : 0;
        __syncthreads();
        pfx[tid] += u;
        __syncthreads();
    }
    int excl = pfx[tid] - v;
    if (tid < nn) {
        rowptr[lo + tid] = ebeg + excl;
        dinv[lo + tid] = rsqrtf((float)v + 1.0f);
        cur[tid] = excl;
    }
    if (b == B - 1 && tid == 0) rowptr[n] = eend;
    __syncthreads();
    if (cnt <= COLCAP) {
        for (int i = tid; i < cnt; i += 256) {
            uint e = ep[ebeg + i];
            int p = atomicAdd(&cur[e >> 24], 1);
            colbuf[p] = (int)(e & 0xFFFFFFu);
        }
        __syncthreads();
        for (int i = tid; i < cnt; i += 256) col[ebeg + i] = colbuf[i];
    } else {
        for (int i = tid; i < cnt; i += 256) {
            uint e = ep[ebeg + i];
            int p = atomicAdd(&cur[e >> 24], 1);
            col[ebeg + p] = (int)(e & 0xFFFFFFu);
        }
    }
}

// h' = bf16((x @ W1 + b1) * dinv[row]), stored as two half-tables.
__global__ __launch_bounds__(256) void k_gemm1_mfma(const float* __restrict__ x,
        const float* __restrict__ W1, const float* __restrict__ b1,
        const float* __restrict__ dinv, ushort* __restrict__ h_bf, int n, int nwt) {
    __shared__ ushort wf[4][8][64][8];  // 32KB
    int t = threadIdx.x;
    for (int i = t; i < 16384; i += 256) {
        int k = i >> 7, nn = i & 127;
        int kt = k >> 5, ct = nn >> 4;
        int lane = ((k >> 3) & 3) * 16 + (nn & 15);
        int j = k & 7;
        wf[kt][ct][lane][j] = f2bf(W1[i]);
    }
    __syncthreads();
    size_t n64 = (size_t)n * 64;
    int wid = t >> 6, lane = t & 63;
    int lrow = lane & 15, lkg = lane >> 4;
    float bias[8];
#pragma unroll
    for (int ct = 0; ct < 8; ++ct) bias[ct] = b1[ct * 16 + lrow];
    int stride = gridDim.x * 4;
    for (int wt = blockIdx.x * 4 + wid; wt < nwt; wt += stride) {
        size_t r0 = (size_t)wt * 16;
        int rr = (int)r0 + lrow;
        if (rr >= n) rr = n - 1;
        short8 ah[4], al[4];
#pragma unroll
        for (int kt = 0; kt < 4; ++kt) {
            const float* p = x + (size_t)rr * 128 + kt * 32 + lkg * 8;
            float va[8];
            *(f32x4*)&va[0] = *(const f32x4*)p;
            *(f32x4*)&va[4] = *(const f32x4*)(p + 4);
#pragma unroll
            for (int j = 0; j < 8; ++j) {
                ushort hb = f2bf(va[j]);
                ah[kt][j] = (short)hb;
                al[kt][j] = (short)f2bf(va[j] - bf2f(hb));
            }
        }
        f32x4 acc[8];
#pragma unroll
        for (int ct = 0; ct < 8; ++ct) {
            float bb = bias[ct];
            acc[ct][0] = bb; acc[ct][1] = bb; acc[ct][2] = bb; acc[ct][3] = bb;
        }
#pragma unroll
        for (int kt = 0; kt < 4; ++kt) {
#pragma unroll
            for (int ct = 0; ct < 8; ++ct) {
                short8 wh = *(const short8*)&wf[kt][ct][lane][0];
                acc[ct] = __builtin_amdgcn_mfma_f32_16x16x32_bf16(ah[kt], wh, acc[ct], 0, 0, 0);
                acc[ct] = __builtin_amdgcn_mfma_f32_16x16x32_bf16(al[kt], wh, acc[ct], 0, 0, 0);
            }
        }
#pragma unroll
        for (int j = 0; j < 4; ++j) {
            int row = (int)r0 + lkg * 4 + j;
            if (row < n) {
                float dr = dinv[row];
#pragma unroll
                for (int ct = 0; ct < 8; ++ct)
                    h_bf[(size_t)(ct >> 2) * n64 + (size_t)row * 64 + (ct & 3) * 16 + lrow]
                        = f2bf(acc[ct][j] * dr);
            }
        }
    }
}

// pull SpMM1 v2: 16-lane node-groups, lane owns 4 cols (uint2), no shuffles.
// 8 gathers in flight per group (32/wave). agg = dinv*(sum h'[src] + h'[node]).
__global__ __launch_bounds__(512) void k_spmm1_csr(const int* __restrict__ rowptr,
        const int* __restrict__ col, const uint2* __restrict__ tbl,
        const float* __restrict__ dinv, uint2* __restrict__ aggq,
        float* __restrict__ accum, int n, int half) {
    __shared__ float redx[64], redq[64];
    int t = threadIdx.x;
    if (t < 64) { redx[t] = 0.f; redq[t] = 0.f; }
    __syncthreads();
    int grp = t >> 4, lid = t & 15;   // 32 groups/block
    int nstride = gridDim.x * 32;
    float sx[4] = {0.f, 0.f, 0.f, 0.f}, sq[4] = {0.f, 0.f, 0.f, 0.f};
    for (int node = blockIdx.x * 32 + grp; node < n; node += nstride) {
        int beg = rowptr[node], end = rowptr[node + 1];
        float a[4] = {0.f, 0.f, 0.f, 0.f};
        add4(tbl[(size_t)node * 16 + lid], a);  // self-loop (h' already *dinv[node])
        int p = beg;
        for (; p + 8 <= end; p += 8) {
            int c0 = col[p],     c1 = col[p + 1], c2 = col[p + 2], c3 = col[p + 3];
            int c4 = col[p + 4], c5 = col[p + 5], c6 = col[p + 6], c7 = col[p + 7];
            uint2 v0 = tbl[(size_t)c0 * 16 + lid];
            uint2 v1 = tbl[(size_t)c1 * 16 + lid];
            uint2 v2 = tbl[(size_t)c2 * 16 + lid];
            uint2 v3 = tbl[(size_t)c3 * 16 + lid];
            uint2 v4 = tbl[(size_t)c4 * 16 + lid];
            uint2 v5 = tbl[(size_t)c5 * 16 + lid];
            uint2 v6 = tbl[(size_t)c6 * 16 + lid];
            uint2 v7 = tbl[(size_t)c7 * 16 + lid];
            add4(v0, a); add4(v1, a); add4(v2, a); add4(v3, a);
            add4(v4, a); add4(v5, a); add4(v6, a); add4(v7, a);
        }
        if (p + 4 <= end) {
            int c0 = col[p], c1 = col[p + 1], c2 = col[p + 2], c3 = col[p + 3];
            uint2 v0 = tbl[(size_t)c0 * 16 + lid];
            uint2 v1 = tbl[(size_t)c1 * 16 + lid];
            uint2 v2 = tbl[(size_t)c2 * 16 + lid];
            uint2 v3 = tbl[(size_t)c3 * 16 + lid];
            add4(v0, a); add4(v1, a); add4(v2, a); add4(v3, a);
            p += 4;
        }
        for (; p < end; ++p)
            add4(tbl[(size_t)col[p] * 16 + lid], a);
        float di = dinv[node];
#pragma unroll
        for (int j = 0; j < 4; ++j) a[j] *= di;
        uint2 pk;
        pk.x = ((uint)f2bf(a[1]) << 16) | (uint)f2bf(a[0]);
        pk.y = ((uint)f2bf(a[3]) << 16) | (uint)f2bf(a[2]);
        aggq[(size_t)node * 32 + half * 16 + lid] = pk;
#pragma unroll
        for (int j = 0; j < 4; ++j) {
            sx[j] += a[j];
            sq[j] = fmaf(a[j], a[j], sq[j]);
        }
    }
#pragma unroll
    for (int j = 0; j < 4; ++j) {
        atomicAdd(&redx[lid * 4 + j], sx[j]);
        atomicAdd(&redq[lid * 4 + j], sq[j]);
    }
    __syncthreads();
    if (t < 64) {
        atomAddF(&accum[half * 64 + t], redx[t]);
        atomAddF(&accum[128 + half * 64 + t], redq[t]);
    }
}

// l_ext rows (192B): [ 64x bf16 l*dinv | f32 s @128 ]; BN finalize fused.
__global__ __launch_bounds__(256) void k_gemm2_mfma(const ushort* __restrict__ agg_bf,
        const float* __restrict__ Wmu, const float* __restrict__ bmu,
        const float* __restrict__ accum, const float* __restrict__ gamma,
        const float* __restrict__ beta, const float* __restrict__ dinv,
        char* __restrict__ l_ext, float inv_n, int n, int nwt) {
    __shared__ ushort wf[4][4][64][8];  // 16KB
    __shared__ float scs[D_HID], shs[D_HID];
    int t = threadIdx.x;
    for (int i = t; i < 8192; i += 256) {
        int k = i >> 6, nn = i & 63;
        int kt = k >> 5, ct = nn >> 4;
        int lane = ((k >> 3) & 3) * 16 + (nn & 15);
        int j = k & 7;
        wf[kt][ct][lane][j] = f2bf(Wmu[i]);
    }
    for (int i = t; i < D_HID; i += 256) {  // fused bnfinal
        float mean = accum[i] * inv_n;
        float var = accum[D_HID + i] * inv_n - mean * mean;
        float sc = gamma[i] * rsqrtf(var + BN_EPS);
        scs[i] = sc;
        shs[i] = beta[i] - mean * sc;
    }
    __syncthreads();
    int wid = t >> 6, lane = t & 63;
    int lrow = lane & 15, lkg = lane >> 4;
    float bias[4];
#pragma unroll
    for (int ct = 0; ct < 4; ++ct) bias[ct] = bmu[ct * 16 + lrow];
    int stride = gridDim.x * 4;
    for (int wt = blockIdx.x * 4 + wid; wt < nwt; wt += stride) {
        size_t r0 = (size_t)wt * 16;
        int rr = (int)r0 + lrow;
        if (rr >= n) rr = n - 1;
        short8 ah[4], al[4];
#pragma unroll
        for (int kt = 0; kt < 4; ++kt) {
            const ushort* p = agg_bf + (size_t)rr * 128 + kt * 32 + lkg * 8;
            short8 raw = *(const short8*)p;
#pragma unroll
            for (int j = 0; j < 8; ++j) {
                int k = kt * 32 + lkg * 8 + j;
                float v = bf2f((ushort)raw[j]) * scs[k] + shs[k];
                v = v > 0.f ? v : SLOPE * v;
                ushort hb = f2bf(v);
                ah[kt][j] = (short)hb;
                al[kt][j] = (short)f2bf(v - bf2f(hb));
            }
        }
        f32x4 acc[4];
#pragma unroll
        for (int ct = 0; ct < 4; ++ct) {
            float bb = bias[ct];
            acc[ct][0] = bb; acc[ct][1] = bb; acc[ct][2] = bb; acc[ct][3] = bb;
        }
#pragma unroll
        for (int kt = 0; kt < 4; ++kt) {
#pragma unroll
            for (int ct = 0; ct < 4; ++ct) {
                short8 wh = *(const short8*)&wf[kt][ct][lane][0];
                acc[ct] = __builtin_amdgcn_mfma_f32_16x16x32_bf16(ah[kt], wh, acc[ct], 0, 0, 0);
                acc[ct] = __builtin_amdgcn_mfma_f32_16x16x32_bf16(al[kt], wh, acc[ct], 0, 0, 0);
            }
        }
#pragma unroll
        for (int j = 0; j < 4; ++j) {
            float ss = acc[0][j] * acc[0][j];
#pragma unroll
            for (int ct = 1; ct < 4; ++ct) ss = fmaf(acc[ct][j], acc[ct][j], ss);
            ss += __shfl_xor(ss, 1, 64);
            ss += __shfl_xor(ss, 2, 64);
            ss += __shfl_xor(ss, 4, 64);
            ss += __shfl_xor(ss, 8, 64);
            float srow = NSCALE / fmaxf(sqrtf(ss), 1e-12f);
            int row = (int)r0 + lkg * 4 + j;
            if (row < n) {
                float dr = dinv[row];
                char* base = l_ext + (size_t)row * LSTRIDE;
#pragma unroll
                for (int ct = 0; ct < 4; ++ct)
                    *(ushort*)(base + (ct * 16 + lrow) * 2) = f2bf(acc[ct][j] * dr);
                if (lrow == 0) *(float*)(base + 128) = srow;
            }
        }
    }
}

// pull SpMM2 v2: 16-lane node-groups, lane owns 4 cols, dual mu/lsd lane-local,
// no shuffles, fused reparam. 8 row-gathers in flight per group.
__global__ __launch_bounds__(512) void k_spmm2_csr(const int* __restrict__ rowptr,
        const int* __restrict__ col, const char* __restrict__ lb,
        const float* __restrict__ dinv, const float* __restrict__ noise,
        float* __restrict__ mu, float* __restrict__ lsd, float* __restrict__ zeta,
        int n) {
    int t = threadIdx.x;
    int grp = t >> 4, lid = t & 15;
    int node = blockIdx.x * 32 + grp;
    if (node >= n) return;
    int beg = rowptr[node], end = rowptr[node + 1];
    float am[4] = {0.f, 0.f, 0.f, 0.f}, al[4] = {0.f, 0.f, 0.f, 0.f};
    {   // self-loop
        const char* rb = lb + (size_t)node * LSTRIDE;
        uint2 v = *(const uint2*)(rb + lid * 8);
        float sv = *(const float*)(rb + 128);
        dacc4(v, sv, 1.f, am, al);
    }
    int p = beg;
    for (; p + 8 <= end; p += 8) {
        int c0 = col[p],     c1 = col[p + 1], c2 = col[p + 2], c3 = col[p + 3];
        int c4 = col[p + 4], c5 = col[p + 5], c6 = col[p + 6], c7 = col[p + 7];
        const char* r0 = lb + (size_t)c0 * LSTRIDE;
        const char* r1 = lb + (size_t)c1 * LSTRIDE;
        const char* r2 = lb + (size_t)c2 * LSTRIDE;
        const char* r3 = lb + (size_t)c3 * LSTRIDE;
        const char* r4 = lb + (size_t)c4 * LSTRIDE;
        const char* r5 = lb + (size_t)c5 * LSTRIDE;
        const char* r6 = lb + (size_t)c6 * LSTRIDE;
        const char* r7 = lb + (size_t)c7 * LSTRIDE;
        uint2 v0 = *(const uint2*)(r0 + lid * 8); float s0 = *(const float*)(r0 + 128);
        uint2 v1 = *(const uint2*)(r1 + lid * 8); float s1 = *(const float*)(r1 + 128);
        uint2 v2 = *(const uint2*)(r2 + lid * 8); float s2 = *(const float*)(r2 + 128);
        uint2 v3 = *(const uint2*)(r3 + lid * 8); float s3 = *(const float*)(r3 + 128);
        uint2 v4 = *(const uint2*)(r4 + lid * 8); float s4 = *(const float*)(r4 + 128);
        uint2 v5 = *(const uint2*)(r5 + lid * 8); float s5 = *(const float*)(r5 + 128);
        uint2 v6 = *(const uint2*)(r6 + lid * 8); float s6 = *(const float*)(r6 + 128);
        uint2 v7 = *(const uint2*)(r7 + lid * 8); float s7 = *(const float*)(r7 + 128);
        dacc4(v0, s0, 1.f, am, al); dacc4(v1, s1, 1.f, am, al);
        dacc4(v2, s2, 1.f, am, al); dacc4(v3, s3, 1.f, am, al);
        dacc4(v4, s4, 1.f, am, al); dacc4(v5, s5, 1.f, am, al);
        dacc4(v6, s6, 1.f, am, al); dacc4(v7, s7, 1.f, am, al);
    }
    if (p + 4 <= end) {
        int c0 = col[p], c1 = col[p + 1], c2 = col[p + 2], c3 = col[p + 3];
        const char* r0 = lb + (size_t)c0 * LSTRIDE;
        const char* r1 = lb + (size_t)c1 * LSTRIDE;
        const char* r2 = lb + (size_t)c2 * LSTRIDE;
        const char* r3 = lb + (size_t)c3 * LSTRIDE;
        uint2 v0 = *(const uint2*)(r0 + lid * 8); float s0 = *(const float*)(r0 + 128);
        uint2 v1 = *(const uint2*)(r1 + lid * 8); float s1 = *(const float*)(r1 + 128);
        uint2 v2 = *(const uint2*)(r2 + lid * 8); float s2 = *(const float*)(r2 + 128);
        uint2 v3 = *(const uint2*)(r3 + lid * 8); float s3 = *(const float*)(r3 + 128);
        dacc4(v0, s0, 1.f, am, al); dacc4(v1, s1, 1.f, am, al);
        dacc4(v2, s2, 1.f, am, al); dacc4(v3, s3, 1.f, am, al);
        p += 4;
    }
    for (; p < end; ++p) {
        const char* r0 = lb + (size_t)col[p] * LSTRIDE;
        uint2 v0 = *(const uint2*)(r0 + lid * 8);
        float s0 = *(const float*)(r0 + 128);
        dacc4(v0, s0, 1.f, am, al);
    }
    float di = dinv[node];
    size_t idx = (size_t)node * 64 + lid * 4;
    f32x4 m, l, z;
#pragma unroll
    for (int j = 0; j < 4; ++j) { m[j] = am[j] * di; l[j] = al[j] * di; }
    f32x4 nz = *(const f32x4*)(noise + idx);
#pragma unroll
    for (int j = 0; j < 4; ++j) z[j] = m[j] + nz[j] * expf(l[j]);
    *(f32x4*)(mu + idx) = m;
    *(f32x4*)(lsd + idx) = l;
    *(f32x4*)(zeta + idx) = z;
}

extern "C" void kernel_launch(void* const* d_in, const int* in_sizes, int n_in,
                              void* d_out, int out_size, void* d_ws, size_t ws_size,
                              hipStream_t stream) {
    const float* x     = (const float*)d_in[0];
    const int*   esrc  = (const int*)d_in[1];
    const int*   edst  = (const int*)d_in[2];
    const float* W1    = (const float*)d_in[3];
    const float* b1    = (const float*)d_in[4];
    const float* gamma = (const float*)d_in[5];
    const float* beta  = (const float*)d_in[6];
    const float* Wmu   = (const float*)d_in[7];
    const float* bmu   = (const float*)d_in[8];
    const float* noise = (const float*)d_in[9];
    int N = in_sizes[0] / D_IN;
    int E = in_sizes[1];
    int B = (N + NB - 1) >> BSH;
    int nwt = (N + 15) / 16;
    int ntile = (E + T1 - 1) / T1;

    float* out  = (float*)d_out;
    float* mu   = out;
    float* lsd  = out + (size_t)N * D_OUT;
    float* zeta = out + 2 * (size_t)N * D_OUT;

    char* ws = (char*)d_ws;
    size_t off = 0;
    auto alloc = [&](size_t bytes) {
        void* p = ws + off;
        off += (bytes + 255) & ~(size_t)255;
        return p;
    };
    float* accum  = (float*)alloc(1024);
    int* bcnt     = (int*)alloc((size_t)B * 4);
    size_t zbytes = off;  // accum + bcnt zeroed
    int* bbase    = (int*)alloc(((size_t)B + 1) * 4);
    int* tailE    = (int*)alloc((size_t)B * 4);
    int* rowptr   = (int*)alloc(((size_t)N + 1) * 4);
    float* dinv   = (float*)alloc((size_t)N * 4);
    uint* ep      = (uint*)alloc((size_t)E * 4);
    int* col      = (int*)alloc((size_t)E * 4);
    ushort* h_bf  = (ushort*)alloc((size_t)N * D_HID * 2);  // two half-tables
    uint2* aggq   = (uint2*)alloc((size_t)N * D_HID * 2);
    char* l_ext   = (char*)alloc((size_t)N * LSTRIDE);

    hipMemsetAsync(d_ws, 0, zbytes, stream);

    size_t n64 = (size_t)N * 64;
    const uint2* tbl0 = (const uint2*)h_bf;
    const uint2* tbl1 = (const uint2*)(h_bf + n64);

    k_bhist<<<ntile, 256, 0, stream>>>(edst, bcnt, E, B);
    k_bscan<<<1, 512, 0, stream>>>(bcnt, bbase, tailE, B);
    k_part<<<ntile, 256, 0, stream>>>(esrc, edst, tailE, ep, E, B);
    k_csr<<<B, 256, 0, stream>>>(ep, bbase, rowptr, dinv, col, N, B);
    k_gemm1_mfma<<<512, 256, 0, stream>>>(x, W1, b1, dinv, h_bf, N, nwt);
    k_spmm1_csr<<<2048, 512, 0, stream>>>(rowptr, col, tbl0, dinv, aggq, accum, N, 0);
    k_spmm1_csr<<<2048, 512, 0, stream>>>(rowptr, col, tbl1, dinv, aggq, accum, N, 1);
    k_gemm2_mfma<<<512, 256, 0, stream>>>((const ushort*)aggq, Wmu, bmu, accum,
                                          gamma, beta, dinv, l_ext, 1.0f / (float)N, N, nwt);
    k_spmm2_csr<<<(N + 31) / 32, 512, 0, stream>>>(rowptr, col, l_ext, dinv, noise, mu, lsd, zeta, N);
}

// Round 12
// 271.465 us; speedup vs baseline: 1.3092x; 1.3092x over previous
//
#include <hip/hip_runtime.h>
#include <hip/hip_bf16.h>
#include <hip/hip_fp16.h>
#include <math.h>

#define D_IN 128
#define D_HID 128
#define D_OUT 64
#define BN_EPS 1e-5f
#define SLOPE 0.01f
#define NSCALE 1.8f

#define BSH 8          // nodes per bucket = 256
#define NB 256
#define T1 4096        // edges per partition tile
#define COLCAP 8192
#define LSTRIDE 192    // bytes per l_ext row: 64 f16 l' + f16 s @128

typedef __attribute__((ext_vector_type(8))) short short8;
typedef __attribute__((ext_vector_type(4))) float f32x4;

__device__ inline void atomAddF(float* p, float v) {
#if defined(__gfx90a__) || defined(__gfx942__) || defined(__gfx950__)
    unsafeAtomicAdd(p, v);
#else
    atomicAdd(p, v);
#endif
}

__device__ inline ushort f2bf(float f) {  // RNE
    union { float f; uint u; } v; v.f = f;
    uint r = v.u + 0x7fff + ((v.u >> 16) & 1);
    return (ushort)(r >> 16);
}
__device__ inline float bf2f(ushort b) {
    union { uint u; float f; } v; v.u = ((uint)b) << 16;
    return v.f;
}
__device__ inline ushort f2h(float f) {
    __half h = __float2half_rn(f);
    return *reinterpret_cast<ushort*>(&h);
}
__device__ inline __half2 u2h2(uint u) { return *reinterpret_cast<__half2*>(&u); }
__device__ inline __half2 shfl_xor_h2(__half2 v, int m) {
    int iv = *reinterpret_cast<int*>(&v);
    int r = __shfl_xor(iv, m, 64);
    return *reinterpret_cast<__half2*>(&r);
}

// packed add of 8 f16 (uint4) into 4 half2 accumulators
__device__ inline void phadd8(uint4 v, __half2 a[4]) {
    a[0] = __hadd2(a[0], u2h2(v.x));
    a[1] = __hadd2(a[1], u2h2(v.y));
    a[2] = __hadd2(a[2], u2h2(v.z));
    a[3] = __hadd2(a[3], u2h2(v.w));
}
// packed dual: am += v ; al += v*s2
__device__ inline void pdacc8(uint4 v, __half2 s2, __half2 am[4], __half2 al[4]) {
    __half2 h0 = u2h2(v.x), h1 = u2h2(v.y), h2 = u2h2(v.z), h3 = u2h2(v.w);
    am[0] = __hadd2(am[0], h0); al[0] = __hfma2(h0, s2, al[0]);
    am[1] = __hadd2(am[1], h1); al[1] = __hfma2(h1, s2, al[1]);
    am[2] = __hadd2(am[2], h2); al[2] = __hfma2(h2, s2, al[2]);
    am[3] = __hadd2(am[3], h3); al[3] = __hfma2(h3, s2, al[3]);
}

// ---- bucket histogram (LDS-staged) -------------------------------------
__global__ __launch_bounds__(256) void k_bhist(const int* __restrict__ dst,
        int* __restrict__ bcnt, int E, int B) {
    __shared__ int h[512];
    for (int i = threadIdx.x; i < 512; i += 256) h[i] = 0;
    __syncthreads();
    int beg = blockIdx.x * T1;
    int end = min(beg + T1, E);
    for (int e = beg + threadIdx.x; e < end; e += 256)
        atomicAdd(&h[dst[e] >> BSH], 1);
    __syncthreads();
    for (int i = threadIdx.x; i < B; i += 256)
        if (h[i]) atomicAdd(&bcnt[i], h[i]);
}

// ---- bucket base scan (single block, B <= 512) -------------------------
__global__ __launch_bounds__(512) void k_bscan(const int* __restrict__ bcnt,
        int* __restrict__ bbase, int* __restrict__ tailE, int B) {
    __shared__ int sh[512];
    int t = threadIdx.x;
    int v = (t < B) ? bcnt[t] : 0;
    sh[t] = v;
    __syncthreads();
    for (int o = 1; o < 512; o <<= 1) {
        int u = (t >= o) ? sh[t - o] : 0;
        __syncthreads();
        sh[t] += u;
        __syncthreads();
    }
    int excl = sh[t] - v;
    if (t < B) { bbase[t] = excl; tailE[t] = excl; }
    if (t == B - 1) bbase[B] = excl + v;
}

// ---- partition edges into bucket regions; ep packed: src | dlocal<<24 --
__global__ __launch_bounds__(256) void k_part(const int* __restrict__ src,
        const int* __restrict__ dst, int* __restrict__ tailE,
        uint* __restrict__ ep, int E, int B) {
    __shared__ int h[512], off[512], gb[512], cur[512];
    __shared__ int ps[256];
    __shared__ int2 ro[T1];
    int tid = threadIdx.x;
    for (int i = tid; i < 512; i += 256) h[i] = 0;
    __syncthreads();
    int beg = blockIdx.x * T1;
    int cnt = min(T1, E - beg);
    int s[16], d[16];
#pragma unroll
    for (int k = 0; k < 16; ++k) {
        int e = beg + tid + k * 256;
        if (e < E) {
            s[k] = src[e]; d[k] = dst[e];
            atomicAdd(&h[d[k] >> BSH], 1);
        } else d[k] = -1;
    }
    __syncthreads();
    int pa = h[2 * tid], pb = h[2 * tid + 1];
    ps[tid] = pa + pb;
    __syncthreads();
    int vv = ps[tid];
    for (int o = 1; o < 256; o <<= 1) {
        int u = (tid >= o) ? ps[tid - o] : 0;
        __syncthreads();
        ps[tid] += u;
        __syncthreads();
    }
    int excl = ps[tid] - vv;
    off[2 * tid] = excl;       off[2 * tid + 1] = excl + pa;
    cur[2 * tid] = excl;       cur[2 * tid + 1] = excl + pa;
    if (2 * tid < B && pa > 0)      gb[2 * tid] = atomicAdd(&tailE[2 * tid], pa);
    if (2 * tid + 1 < B && pb > 0)  gb[2 * tid + 1] = atomicAdd(&tailE[2 * tid + 1], pb);
    __syncthreads();
#pragma unroll
    for (int k = 0; k < 16; ++k) {
        if (d[k] >= 0) {
            int b = d[k] >> BSH;
            int p = atomicAdd(&cur[b], 1);
            ro[p] = make_int2(s[k], d[k]);
        }
    }
    __syncthreads();
    for (int i = tid; i < cnt; i += 256) {
        int2 e = ro[i];
        int b = e.y >> BSH;
        ep[gb[b] + (i - off[b])] = (uint)e.x | ((uint)(e.y & (NB - 1)) << 24);
    }
}

// ---- per-bucket: deg/rowptr/dinv + CSR col build in LDS ----------------
__global__ __launch_bounds__(256) void k_csr(const uint* __restrict__ ep,
        const int* __restrict__ bbase, int* __restrict__ rowptr,
        float* __restrict__ dinv, int* __restrict__ col, int n, int B) {
    int b = blockIdx.x;
    int lo = b << BSH;
    int hi = min(lo + NB, n);
    int nn = hi - lo;
    int ebeg = bbase[b], eend = bbase[b + 1], cnt = eend - ebeg;
    __shared__ int h[NB], pfx[NB], cur[NB];
    __shared__ int colbuf[COLCAP];
    int tid = threadIdx.x;
    if (tid < NB) h[tid] = 0;
    __syncthreads();
    for (int i = tid; i < cnt; i += 256)
        atomicAdd(&h[ep[ebeg + i] >> 24], 1);
    __syncthreads();
    int v = (tid < nn) ? h[tid] : 0;
    pfx[tid] = v;
    __syncthreads();
    for (int o = 1; o < 256; o <<= 1) {
        int u = (tid >= o) ? pfx[tid - o] : 0;
        __syncthreads();
        pfx[tid] += u;
        __syncthreads();
    }
    int excl = pfx[tid] - v;
    if (tid < nn) {
        rowptr[lo + tid] = ebeg + excl;
        dinv[lo + tid] = rsqrtf((float)v + 1.0f);
        cur[tid] = excl;
    }
    if (b == B - 1 && tid == 0) rowptr[n] = eend;
    __syncthreads();
    if (cnt <= COLCAP) {
        for (int i = tid; i < cnt; i += 256) {
            uint e = ep[ebeg + i];
            int p = atomicAdd(&cur[e >> 24], 1);
            colbuf[p] = (int)(e & 0xFFFFFFu);
        }
        __syncthreads();
        for (int i = tid; i < cnt; i += 256) col[ebeg + i] = colbuf[i];
    } else {
        for (int i = tid; i < cnt; i += 256) {
            uint e = ep[ebeg + i];
            int p = atomicAdd(&cur[e >> 24], 1);
            col[ebeg + p] = (int)(e & 0xFFFFFFu);
        }
    }
}

// h' = f16((x @ W1 + b1) * dinv[row]), row-major 128 cols (256B rows).
__global__ __launch_bounds__(256) void k_gemm1_mfma(const float* __restrict__ x,
        const float* __restrict__ W1, const float* __restrict__ b1,
        const float* __restrict__ dinv, ushort* __restrict__ h16, int n, int nwt) {
    __shared__ ushort wf[4][8][64][8];  // 32KB
    int t = threadIdx.x;
    for (int i = t; i < 16384; i += 256) {
        int k = i >> 7, nn = i & 127;
        int kt = k >> 5, ct = nn >> 4;
        int lane = ((k >> 3) & 3) * 16 + (nn & 15);
        int j = k & 7;
        wf[kt][ct][lane][j] = f2bf(W1[i]);
    }
    __syncthreads();
    int wid = t >> 6, lane = t & 63;
    int lrow = lane & 15, lkg = lane >> 4;
    float bias[8];
#pragma unroll
    for (int ct = 0; ct < 8; ++ct) bias[ct] = b1[ct * 16 + lrow];
    int stride = gridDim.x * 4;
    for (int wt = blockIdx.x * 4 + wid; wt < nwt; wt += stride) {
        size_t r0 = (size_t)wt * 16;
        int rr = (int)r0 + lrow;
        if (rr >= n) rr = n - 1;
        short8 ah[4], al[4];
#pragma unroll
        for (int kt = 0; kt < 4; ++kt) {
            const float* p = x + (size_t)rr * 128 + kt * 32 + lkg * 8;
            float va[8];
            *(f32x4*)&va[0] = *(const f32x4*)p;
            *(f32x4*)&va[4] = *(const f32x4*)(p + 4);
#pragma unroll
            for (int j = 0; j < 8; ++j) {
                ushort hb = f2bf(va[j]);
                ah[kt][j] = (short)hb;
                al[kt][j] = (short)f2bf(va[j] - bf2f(hb));
            }
        }
        f32x4 acc[8];
#pragma unroll
        for (int ct = 0; ct < 8; ++ct) {
            float bb = bias[ct];
            acc[ct][0] = bb; acc[ct][1] = bb; acc[ct][2] = bb; acc[ct][3] = bb;
        }
#pragma unroll
        for (int kt = 0; kt < 4; ++kt) {
#pragma unroll
            for (int ct = 0; ct < 8; ++ct) {
                short8 wh = *(const short8*)&wf[kt][ct][lane][0];
                acc[ct] = __builtin_amdgcn_mfma_f32_16x16x32_bf16(ah[kt], wh, acc[ct], 0, 0, 0);
                acc[ct] = __builtin_amdgcn_mfma_f32_16x16x32_bf16(al[kt], wh, acc[ct], 0, 0, 0);
            }
        }
#pragma unroll
        for (int j = 0; j < 4; ++j) {
            int row = (int)r0 + lkg * 4 + j;
            if (row < n) {
                float dr = dinv[row];
#pragma unroll
                for (int ct = 0; ct < 8; ++ct)
                    h16[(size_t)row * 128 + ct * 16 + lrow] = f2h(acc[ct][j] * dr);
            }
        }
    }
}

// pull SpMM1: quarter-wave (16 lanes x uint4 = 256B f16 row), packed half2 accum,
// 16 edges in flight/wave. agg = dinv*(sum h'[src] + h'[node]) -> bf16; BN stats.
__global__ __launch_bounds__(512) void k_spmm1_csr(const int* __restrict__ rowptr,
        const int* __restrict__ col, const uint4* __restrict__ tbl,
        const float* __restrict__ dinv, uint4* __restrict__ agg4,
        float* __restrict__ accum, int n) {
    __shared__ float red[8][16][8];
    int t = threadIdx.x;
    int wid = t >> 6, lane = t & 63;
    int q = lane >> 4, g = lane & 15;
    int gw = blockIdx.x * 8 + wid;
    int nw = gridDim.x * 8;
    float sx[8], sq[8];
#pragma unroll
    for (int j = 0; j < 8; ++j) { sx[j] = 0.f; sq[j] = 0.f; }
    __half2 hz = __float2half2_rn(0.f);
    for (int node = gw; node < n; node += nw) {
        int beg = rowptr[node], end = rowptr[node + 1];
        __half2 a2[4] = {hz, hz, hz, hz};
        if (q == 0) phadd8(tbl[(size_t)node * 16 + g], a2);  // self-loop
        int p = beg;
        for (; p + 16 <= end; p += 16) {
            int c0 = col[p + q], c1 = col[p + 4 + q];
            int c2 = col[p + 8 + q], c3 = col[p + 12 + q];
            uint4 v0 = tbl[(size_t)c0 * 16 + g];
            uint4 v1 = tbl[(size_t)c1 * 16 + g];
            uint4 v2 = tbl[(size_t)c2 * 16 + g];
            uint4 v3 = tbl[(size_t)c3 * 16 + g];
            phadd8(v0, a2); phadd8(v1, a2); phadd8(v2, a2); phadd8(v3, a2);
        }
        if (p + 8 <= end) {
            int c0 = col[p + q], c1 = col[p + 4 + q];
            uint4 v0 = tbl[(size_t)c0 * 16 + g];
            uint4 v1 = tbl[(size_t)c1 * 16 + g];
            phadd8(v0, a2); phadd8(v1, a2);
            p += 8;
        }
        if (p < end) {
            int i0 = p + q, i1 = p + 4 + q;
            int c0 = col[i0 < end ? i0 : end - 1];
            int c1 = col[i1 < end ? i1 : end - 1];
            uint4 v0 = tbl[(size_t)c0 * 16 + g];
            uint4 v1 = tbl[(size_t)c1 * 16 + g];
            if (i0 < end) phadd8(v0, a2);
            if (i1 < end) phadd8(v1, a2);
        }
        float a[8];
#pragma unroll
        for (int j = 0; j < 4; ++j) {
            float2 f = __half22float2(a2[j]);
            a[2 * j] = f.x; a[2 * j + 1] = f.y;
        }
#pragma unroll
        for (int j = 0; j < 8; ++j) {
            a[j] += __shfl_xor(a[j], 16, 64);
            a[j] += __shfl_xor(a[j], 32, 64);
        }
        if (q == 0) {
            float di = dinv[node];
#pragma unroll
            for (int j = 0; j < 8; ++j) a[j] *= di;
            uint4 pk;
            pk.x = ((uint)f2bf(a[1]) << 16) | (uint)f2bf(a[0]);
            pk.y = ((uint)f2bf(a[3]) << 16) | (uint)f2bf(a[2]);
            pk.z = ((uint)f2bf(a[5]) << 16) | (uint)f2bf(a[4]);
            pk.w = ((uint)f2bf(a[7]) << 16) | (uint)f2bf(a[6]);
            agg4[(size_t)node * 16 + g] = pk;
#pragma unroll
            for (int j = 0; j < 8; ++j) {
                sx[j] += a[j];
                sq[j] = fmaf(a[j], a[j], sq[j]);
            }
        }
    }
    if (q == 0) {
#pragma unroll
        for (int j = 0; j < 8; ++j) red[wid][g][j] = sx[j];
    }
    __syncthreads();
    if (t < 128) {
        float v = 0.f;
        for (int w = 0; w < 8; ++w) v += red[w][t >> 3][t & 7];
        atomAddF(&accum[t], v);
    }
    __syncthreads();
    if (q == 0) {
#pragma unroll
        for (int j = 0; j < 8; ++j) red[wid][g][j] = sq[j];
    }
    __syncthreads();
    if (t < 128) {
        float v = 0.f;
        for (int w = 0; w < 8; ++w) v += red[w][t >> 3][t & 7];
        atomAddF(&accum[128 + t], v);
    }
}

// l_ext rows (192B): [ 64x f16 l*dinv | f16 s @128 ]; BN finalize fused.
__global__ __launch_bounds__(256) void k_gemm2_mfma(const ushort* __restrict__ agg_bf,
        const float* __restrict__ Wmu, const float* __restrict__ bmu,
        const float* __restrict__ accum, const float* __restrict__ gamma,
        const float* __restrict__ beta, const float* __restrict__ dinv,
        char* __restrict__ l_ext, float inv_n, int n, int nwt) {
    __shared__ ushort wf[4][4][64][8];  // 16KB
    __shared__ float scs[D_HID], shs[D_HID];
    int t = threadIdx.x;
    for (int i = t; i < 8192; i += 256) {
        int k = i >> 6, nn = i & 63;
        int kt = k >> 5, ct = nn >> 4;
        int lane = ((k >> 3) & 3) * 16 + (nn & 15);
        int j = k & 7;
        wf[kt][ct][lane][j] = f2bf(Wmu[i]);
    }
    for (int i = t; i < D_HID; i += 256) {  // fused bnfinal
        float mean = accum[i] * inv_n;
        float var = accum[D_HID + i] * inv_n - mean * mean;
        float sc = gamma[i] * rsqrtf(var + BN_EPS);
        scs[i] = sc;
        shs[i] = beta[i] - mean * sc;
    }
    __syncthreads();
    int wid = t >> 6, lane = t & 63;
    int lrow = lane & 15, lkg = lane >> 4;
    float bias[4];
#pragma unroll
    for (int ct = 0; ct < 4; ++ct) bias[ct] = bmu[ct * 16 + lrow];
    int stride = gridDim.x * 4;
    for (int wt = blockIdx.x * 4 + wid; wt < nwt; wt += stride) {
        size_t r0 = (size_t)wt * 16;
        int rr = (int)r0 + lrow;
        if (rr >= n) rr = n - 1;
        short8 ah[4], al[4];
#pragma unroll
        for (int kt = 0; kt < 4; ++kt) {
            const ushort* p = agg_bf + (size_t)rr * 128 + kt * 32 + lkg * 8;
            short8 raw = *(const short8*)p;
#pragma unroll
            for (int j = 0; j < 8; ++j) {
                int k = kt * 32 + lkg * 8 + j;
                float v = bf2f((ushort)raw[j]) * scs[k] + shs[k];
                v = v > 0.f ? v : SLOPE * v;
                ushort hb = f2bf(v);
                ah[kt][j] = (short)hb;
                al[kt][j] = (short)f2bf(v - bf2f(hb));
            }
        }
        f32x4 acc[4];
#pragma unroll
        for (int ct = 0; ct < 4; ++ct) {
            float bb = bias[ct];
            acc[ct][0] = bb; acc[ct][1] = bb; acc[ct][2] = bb; acc[ct][3] = bb;
        }
#pragma unroll
        for (int kt = 0; kt < 4; ++kt) {
#pragma unroll
            for (int ct = 0; ct < 4; ++ct) {
                short8 wh = *(const short8*)&wf[kt][ct][lane][0];
                acc[ct] = __builtin_amdgcn_mfma_f32_16x16x32_bf16(ah[kt], wh, acc[ct], 0, 0, 0);
                acc[ct] = __builtin_amdgcn_mfma_f32_16x16x32_bf16(al[kt], wh, acc[ct], 0, 0, 0);
            }
        }
#pragma unroll
        for (int j = 0; j < 4; ++j) {
            float ss = acc[0][j] * acc[0][j];
#pragma unroll
            for (int ct = 1; ct < 4; ++ct) ss = fmaf(acc[ct][j], acc[ct][j], ss);
            ss += __shfl_xor(ss, 1, 64);
            ss += __shfl_xor(ss, 2, 64);
            ss += __shfl_xor(ss, 4, 64);
            ss += __shfl_xor(ss, 8, 64);
            float srow = NSCALE / fmaxf(sqrtf(ss), 1e-12f);
            int row = (int)r0 + lkg * 4 + j;
            if (row < n) {
                float dr = dinv[row];
                char* base = l_ext + (size_t)row * LSTRIDE;
#pragma unroll
                for (int ct = 0; ct < 4; ++ct)
                    *(ushort*)(base + (ct * 16 + lrow) * 2) = f2h(acc[ct][j] * dr);
                if (lrow == 0) *(ushort*)(base + 128) = f2h(srow);
            }
        }
    }
}

// pull SpMM2: octet-per-edge (8 lanes x uint4 = 128B f16), packed half2 dual
// accum (mu & l*s), packed octet reduce, fused reparam.
__global__ __launch_bounds__(512) void k_spmm2_csr(const int* __restrict__ rowptr,
        const int* __restrict__ col, const char* __restrict__ lb,
        const float* __restrict__ dinv, const float* __restrict__ noise,
        float* __restrict__ mu, float* __restrict__ lsd, float* __restrict__ zeta,
        int n) {
    int node = blockIdx.x * 8 + ((int)threadIdx.x >> 6);
    if (node >= n) return;
    int lane = threadIdx.x & 63;
    int oct = lane >> 3, g = lane & 7;  // lane holds cols 8g..8g+7
    int beg = rowptr[node], end = rowptr[node + 1];
    __half2 hz = __float2half2_rn(0.f);
    __half2 am2[4] = {hz, hz, hz, hz}, al2[4] = {hz, hz, hz, hz};
    if (oct == 0) {  // self-loop
        const char* rb = lb + (size_t)node * LSTRIDE;
        uint4 v = *(const uint4*)(rb + g * 16);
        ushort sr = *(const ushort*)(rb + 128);
        __half2 s2 = __half2half2(*reinterpret_cast<const __half*>(&sr));
        pdacc8(v, s2, am2, al2);
    }
    int p = beg;
    for (; p + 16 <= end; p += 16) {
        int c0 = col[p + oct], c1 = col[p + 8 + oct];
        const char* r0 = lb + (size_t)c0 * LSTRIDE;
        const char* r1 = lb + (size_t)c1 * LSTRIDE;
        uint4 v0 = *(const uint4*)(r0 + g * 16);
        ushort sr0 = *(const ushort*)(r0 + 128);
        uint4 v1 = *(const uint4*)(r1 + g * 16);
        ushort sr1 = *(const ushort*)(r1 + 128);
        __half2 s20 = __half2half2(*reinterpret_cast<const __half*>(&sr0));
        __half2 s21 = __half2half2(*reinterpret_cast<const __half*>(&sr1));
        pdacc8(v0, s20, am2, al2);
        pdacc8(v1, s21, am2, al2);
    }
    if (p + 8 <= end) {
        int c0 = col[p + oct];
        const char* r0 = lb + (size_t)c0 * LSTRIDE;
        uint4 v0 = *(const uint4*)(r0 + g * 16);
        ushort sr0 = *(const ushort*)(r0 + 128);
        __half2 s20 = __half2half2(*reinterpret_cast<const __half*>(&sr0));
        pdacc8(v0, s20, am2, al2);
        p += 8;
    }
    if (p < end) {
        int i0 = p + oct;
        int c0 = col[i0 < end ? i0 : end - 1];
        const char* r0 = lb + (size_t)c0 * LSTRIDE;
        uint4 v0 = *(const uint4*)(r0 + g * 16);
        ushort sr0 = *(const ushort*)(r0 + 128);
        __half2 s20 = __half2half2(*reinterpret_cast<const __half*>(&sr0));
        if (i0 < end) pdacc8(v0, s20, am2, al2);
    }
    // packed reduce across octets
#pragma unroll
    for (int j = 0; j < 4; ++j) {
        am2[j] = __hadd2(am2[j], shfl_xor_h2(am2[j], 8));
        am2[j] = __hadd2(am2[j], shfl_xor_h2(am2[j], 16));
        am2[j] = __hadd2(am2[j], shfl_xor_h2(am2[j], 32));
        al2[j] = __hadd2(al2[j], shfl_xor_h2(al2[j], 8));
        al2[j] = __hadd2(al2[j], shfl_xor_h2(al2[j], 16));
        al2[j] = __hadd2(al2[j], shfl_xor_h2(al2[j], 32));
    }
    if (lane < 8) {
        float di = dinv[node];
        size_t idx = (size_t)node * 64 + lane * 8;
        float am[8], al[8];
#pragma unroll
        for (int j = 0; j < 4; ++j) {
            float2 fm = __half22float2(am2[j]);
            float2 fl = __half22float2(al2[j]);
            am[2 * j] = fm.x * di; am[2 * j + 1] = fm.y * di;
            al[2 * j] = fl.x * di; al[2 * j + 1] = fl.y * di;
        }
        f32x4 n0 = *(const f32x4*)(noise + idx);
        f32x4 n1 = *(const f32x4*)(noise + idx + 4);
        f32x4 m0, m1, l0, l1, z0, z1;
#pragma unroll
        for (int j = 0; j < 4; ++j) {
            m0[j] = am[j];     m1[j] = am[j + 4];
            l0[j] = al[j];     l1[j] = al[j + 4];
            z0[j] = m0[j] + n0[j] * expf(l0[j]);
            z1[j] = m1[j] + n1[j] * expf(l1[j]);
        }
        *(f32x4*)(mu + idx) = m0;   *(f32x4*)(mu + idx + 4) = m1;
        *(f32x4*)(lsd + idx) = l0;  *(f32x4*)(lsd + idx + 4) = l1;
        *(f32x4*)(zeta + idx) = z0; *(f32x4*)(zeta + idx + 4) = z1;
    }
}

extern "C" void kernel_launch(void* const* d_in, const int* in_sizes, int n_in,
                              void* d_out, int out_size, void* d_ws, size_t ws_size,
                              hipStream_t stream) {
    const float* x     = (const float*)d_in[0];
    const int*   esrc  = (const int*)d_in[1];
    const int*   edst  = (const int*)d_in[2];
    const float* W1    = (const float*)d_in[3];
    const float* b1    = (const float*)d_in[4];
    const float* gamma = (const float*)d_in[5];
    const float* beta  = (const float*)d_in[6];
    const float* Wmu   = (const float*)d_in[7];
    const float* bmu   = (const float*)d_in[8];
    const float* noise = (const float*)d_in[9];
    int N = in_sizes[0] / D_IN;
    int E = in_sizes[1];
    int B = (N + NB - 1) >> BSH;
    int nwt = (N + 15) / 16;
    int ntile = (E + T1 - 1) / T1;

    float* out  = (float*)d_out;
    float* mu   = out;
    float* lsd  = out + (size_t)N * D_OUT;
    float* zeta = out + 2 * (size_t)N * D_OUT;

    char* ws = (char*)d_ws;
    size_t off = 0;
    auto alloc = [&](size_t bytes) {
        void* p = ws + off;
        off += (bytes + 255) & ~(size_t)255;
        return p;
    };
    float* accum  = (float*)alloc(1024);
    int* bcnt     = (int*)alloc((size_t)B * 4);
    size_t zbytes = off;  // accum + bcnt zeroed
    int* bbase    = (int*)alloc(((size_t)B + 1) * 4);
    int* tailE    = (int*)alloc((size_t)B * 4);
    int* rowptr   = (int*)alloc(((size_t)N + 1) * 4);
    float* dinv   = (float*)alloc((size_t)N * 4);
    uint* ep      = (uint*)alloc((size_t)E * 4);
    int* col      = (int*)alloc((size_t)E * 4);
    ushort* h16   = (ushort*)alloc((size_t)N * D_HID * 2);
    uint4* agg4   = (uint4*)alloc((size_t)N * D_HID * 2);
    char* l_ext   = (char*)alloc((size_t)N * LSTRIDE);

    hipMemsetAsync(d_ws, 0, zbytes, stream);

    k_bhist<<<ntile, 256, 0, stream>>>(edst, bcnt, E, B);
    k_bscan<<<1, 512, 0, stream>>>(bcnt, bbase, tailE, B);
    k_part<<<ntile, 256, 0, stream>>>(esrc, edst, tailE, ep, E, B);
    k_csr<<<B, 256, 0, stream>>>(ep, bbase, rowptr, dinv, col, N, B);
    k_gemm1_mfma<<<512, 256, 0, stream>>>(x, W1, b1, dinv, h16, N, nwt);
    k_spmm1_csr<<<2048, 512, 0, stream>>>(rowptr, col, (const uint4*)h16, dinv, agg4, accum, N);
    k_gemm2_mfma<<<512, 256, 0, stream>>>((const ushort*)agg4, Wmu, bmu, accum,
                                          gamma, beta, dinv, l_ext, 1.0f / (float)N, N, nwt);
    k_spmm2_csr<<<(N + 7) / 8, 512, 0, stream>>>(rowptr, col, l_ext, dinv, noise, mu, lsd, zeta, N);
}

// Round 13
// 259.966 us; speedup vs baseline: 1.3671x; 1.0442x over previous
//
#include <hip/hip_runtime.h>
#include <hip/hip_bf16.h>
#include <hip/hip_fp16.h>
#include <math.h>

#define D_IN 128
#define D_HID 128
#define D_OUT 64
#define BN_EPS 1e-5f
#define SLOPE 0.01f
#define NSCALE 1.8f

#define BSH 8          // nodes per bucket = 256
#define NB 256
#define T1 4096        // edges per partition tile
#define COLCAP 8192
#define LSTRIDE 192    // bytes per l_ext row: 64 f16 l' + f16 s @128

typedef __attribute__((ext_vector_type(8))) short short8;
typedef __attribute__((ext_vector_type(4))) float f32x4;

__device__ inline void atomAddF(float* p, float v) {
#if defined(__gfx90a__) || defined(__gfx942__) || defined(__gfx950__)
    unsafeAtomicAdd(p, v);
#else
    atomicAdd(p, v);
#endif
}

__device__ inline ushort f2bf(float f) {  // RNE
    union { float f; uint u; } v; v.f = f;
    uint r = v.u + 0x7fff + ((v.u >> 16) & 1);
    return (ushort)(r >> 16);
}
__device__ inline float bf2f(ushort b) {
    union { uint u; float f; } v; v.u = ((uint)b) << 16;
    return v.f;
}
__device__ inline float bflo(uint u) { return __uint_as_float(u << 16); }
__device__ inline float bfhi(uint u) { return __uint_as_float(u & 0xffff0000u); }
__device__ inline ushort f2h(float f) {
    __half h = __float2half_rn(f);
    return *reinterpret_cast<ushort*>(&h);
}
__device__ inline __half2 u2h2(uint u) { return *reinterpret_cast<__half2*>(&u); }
__device__ inline __half2 shfl_xor_h2(__half2 v, int m) {
    int iv = *reinterpret_cast<int*>(&v);
    int r = __shfl_xor(iv, m, 64);
    return *reinterpret_cast<__half2*>(&r);
}

// bf16 row add: 8 cols (uint4) into 8 f32 accumulators
__device__ inline void add8(uint4 v, float a[8]) {
    a[0] += bflo(v.x); a[1] += bfhi(v.x);
    a[2] += bflo(v.y); a[3] += bfhi(v.y);
    a[4] += bflo(v.z); a[5] += bfhi(v.z);
    a[6] += bflo(v.w); a[7] += bfhi(v.w);
}
// packed dual: am += v ; al += v*s2  (f16)
__device__ inline void pdacc8(uint4 v, __half2 s2, __half2 am[4], __half2 al[4]) {
    __half2 h0 = u2h2(v.x), h1 = u2h2(v.y), h2 = u2h2(v.z), h3 = u2h2(v.w);
    am[0] = __hadd2(am[0], h0); al[0] = __hfma2(h0, s2, al[0]);
    am[1] = __hadd2(am[1], h1); al[1] = __hfma2(h1, s2, al[1]);
    am[2] = __hadd2(am[2], h2); al[2] = __hfma2(h2, s2, al[2]);
    am[3] = __hadd2(am[3], h3); al[3] = __hfma2(h3, s2, al[3]);
}

// ---- bucket histogram (LDS-staged) -------------------------------------
__global__ __launch_bounds__(256) void k_bhist(const int* __restrict__ dst,
        int* __restrict__ bcnt, int E, int B) {
    __shared__ int h[512];
    for (int i = threadIdx.x; i < 512; i += 256) h[i] = 0;
    __syncthreads();
    int beg = blockIdx.x * T1;
    int end = min(beg + T1, E);
    for (int e = beg + threadIdx.x; e < end; e += 256)
        atomicAdd(&h[dst[e] >> BSH], 1);
    __syncthreads();
    for (int i = threadIdx.x; i < B; i += 256)
        if (h[i]) atomicAdd(&bcnt[i], h[i]);
}

// ---- bucket base scan (single block, B <= 512) -------------------------
__global__ __launch_bounds__(512) void k_bscan(const int* __restrict__ bcnt,
        int* __restrict__ bbase, int* __restrict__ tailE, int B) {
    __shared__ int sh[512];
    int t = threadIdx.x;
    int v = (t < B) ? bcnt[t] : 0;
    sh[t] = v;
    __syncthreads();
    for (int o = 1; o < 512; o <<= 1) {
        int u = (t >= o) ? sh[t - o] : 0;
        __syncthreads();
        sh[t] += u;
        __syncthreads();
    }
    int excl = sh[t] - v;
    if (t < B) { bbase[t] = excl; tailE[t] = excl; }
    if (t == B - 1) bbase[B] = excl + v;
}

// ---- partition edges into bucket regions; ep packed: src | dlocal<<24 --
__global__ __launch_bounds__(256) void k_part(const int* __restrict__ src,
        const int* __restrict__ dst, int* __restrict__ tailE,
        uint* __restrict__ ep, int E, int B) {
    __shared__ int h[512], off[512], gb[512], cur[512];
    __shared__ int ps[256];
    __shared__ int2 ro[T1];
    int tid = threadIdx.x;
    for (int i = tid; i < 512; i += 256) h[i] = 0;
    __syncthreads();
    int beg = blockIdx.x * T1;
    int cnt = min(T1, E - beg);
    int s[16], d[16];
#pragma unroll
    for (int k = 0; k < 16; ++k) {
        int e = beg + tid + k * 256;
        if (e < E) {
            s[k] = src[e]; d[k] = dst[e];
            atomicAdd(&h[d[k] >> BSH], 1);
        } else d[k] = -1;
    }
    __syncthreads();
    int pa = h[2 * tid], pb = h[2 * tid + 1];
    ps[tid] = pa + pb;
    __syncthreads();
    int vv = ps[tid];
    for (int o = 1; o < 256; o <<= 1) {
        int u = (tid >= o) ? ps[tid - o] : 0;
        __syncthreads();
        ps[tid] += u;
        __syncthreads();
    }
    int excl = ps[tid] - vv;
    off[2 * tid] = excl;       off[2 * tid + 1] = excl + pa;
    cur[2 * tid] = excl;       cur[2 * tid + 1] = excl + pa;
    if (2 * tid < B && pa > 0)      gb[2 * tid] = atomicAdd(&tailE[2 * tid], pa);
    if (2 * tid + 1 < B && pb > 0)  gb[2 * tid + 1] = atomicAdd(&tailE[2 * tid + 1], pb);
    __syncthreads();
#pragma unroll
    for (int k = 0; k < 16; ++k) {
        if (d[k] >= 0) {
            int b = d[k] >> BSH;
            int p = atomicAdd(&cur[b], 1);
            ro[p] = make_int2(s[k], d[k]);
        }
    }
    __syncthreads();
    for (int i = tid; i < cnt; i += 256) {
        int2 e = ro[i];
        int b = e.y >> BSH;
        ep[gb[b] + (i - off[b])] = (uint)e.x | ((uint)(e.y & (NB - 1)) << 24);
    }
}

// ---- per-bucket: deg/rowptr/dinv + CSR col build in LDS ----------------
__global__ __launch_bounds__(256) void k_csr(const uint* __restrict__ ep,
        const int* __restrict__ bbase, int* __restrict__ rowptr,
        float* __restrict__ dinv, int* __restrict__ col, int n, int B) {
    int b = blockIdx.x;
    int lo = b << BSH;
    int hi = min(lo + NB, n);
    int nn = hi - lo;
    int ebeg = bbase[b], eend = bbase[b + 1], cnt = eend - ebeg;
    __shared__ int h[NB], pfx[NB], cur[NB];
    __shared__ int colbuf[COLCAP];
    int tid = threadIdx.x;
    if (tid < NB) h[tid] = 0;
    __syncthreads();
    for (int i = tid; i < cnt; i += 256)
        atomicAdd(&h[ep[ebeg + i] >> 24], 1);
    __syncthreads();
    int v = (tid < nn) ? h[tid] : 0;
    pfx[tid] = v;
    __syncthreads();
    for (int o = 1; o < 256; o <<= 1) {
        int u = (tid >= o) ? pfx[tid - o] : 0;
        __syncthreads();
        pfx[tid] += u;
        __syncthreads();
    }
    int excl = pfx[tid] - v;
    if (tid < nn) {
        rowptr[lo + tid] = ebeg + excl;
        dinv[lo + tid] = rsqrtf((float)v + 1.0f);
        cur[tid] = excl;
    }
    if (b == B - 1 && tid == 0) rowptr[n] = eend;
    __syncthreads();
    if (cnt <= COLCAP) {
        for (int i = tid; i < cnt; i += 256) {
            uint e = ep[ebeg + i];
            int p = atomicAdd(&cur[e >> 24], 1);
            colbuf[p] = (int)(e & 0xFFFFFFu);
        }
        __syncthreads();
        for (int i = tid; i < cnt; i += 256) col[ebeg + i] = colbuf[i];
    } else {
        for (int i = tid; i < cnt; i += 256) {
            uint e = ep[ebeg + i];
            int p = atomicAdd(&cur[e >> 24], 1);
            col[ebeg + p] = (int)(e & 0xFFFFFFu);
        }
    }
}

// h' = bf16((x @ W1 + b1) * dinv[row]), row-major 128 cols (256B rows).
__global__ __launch_bounds__(256) void k_gemm1_mfma(const float* __restrict__ x,
        const float* __restrict__ W1, const float* __restrict__ b1,
        const float* __restrict__ dinv, ushort* __restrict__ h_bf, int n, int nwt) {
    __shared__ ushort wf[4][8][64][8];  // 32KB
    int t = threadIdx.x;
    for (int i = t; i < 16384; i += 256) {
        int k = i >> 7, nn = i & 127;
        int kt = k >> 5, ct = nn >> 4;
        int lane = ((k >> 3) & 3) * 16 + (nn & 15);
        int j = k & 7;
        wf[kt][ct][lane][j] = f2bf(W1[i]);
    }
    __syncthreads();
    int wid = t >> 6, lane = t & 63;
    int lrow = lane & 15, lkg = lane >> 4;
    float bias[8];
#pragma unroll
    for (int ct = 0; ct < 8; ++ct) bias[ct] = b1[ct * 16 + lrow];
    int stride = gridDim.x * 4;
    for (int wt = blockIdx.x * 4 + wid; wt < nwt; wt += stride) {
        size_t r0 = (size_t)wt * 16;
        int rr = (int)r0 + lrow;
        if (rr >= n) rr = n - 1;
        short8 ah[4], al[4];
#pragma unroll
        for (int kt = 0; kt < 4; ++kt) {
            const float* p = x + (size_t)rr * 128 + kt * 32 + lkg * 8;
            float va[8];
            *(f32x4*)&va[0] = *(const f32x4*)p;
            *(f32x4*)&va[4] = *(const f32x4*)(p + 4);
#pragma unroll
            for (int j = 0; j < 8; ++j) {
                ushort hb = f2bf(va[j]);
                ah[kt][j] = (short)hb;
                al[kt][j] = (short)f2bf(va[j] - bf2f(hb));
            }
        }
        f32x4 acc[8];
#pragma unroll
        for (int ct = 0; ct < 8; ++ct) {
            float bb = bias[ct];
            acc[ct][0] = bb; acc[ct][1] = bb; acc[ct][2] = bb; acc[ct][3] = bb;
        }
#pragma unroll
        for (int kt = 0; kt < 4; ++kt) {
#pragma unroll
            for (int ct = 0; ct < 8; ++ct) {
                short8 wh = *(const short8*)&wf[kt][ct][lane][0];
                acc[ct] = __builtin_amdgcn_mfma_f32_16x16x32_bf16(ah[kt], wh, acc[ct], 0, 0, 0);
                acc[ct] = __builtin_amdgcn_mfma_f32_16x16x32_bf16(al[kt], wh, acc[ct], 0, 0, 0);
            }
        }
#pragma unroll
        for (int j = 0; j < 4; ++j) {
            int row = (int)r0 + lkg * 4 + j;
            if (row < n) {
                float dr = dinv[row];
#pragma unroll
                for (int ct = 0; ct < 8; ++ct)
                    h_bf[(size_t)row * 128 + ct * 16 + lrow] = f2bf(acc[ct][j] * dr);
            }
        }
    }
}

// pull SpMM1: quarter-wave (16 lanes x uint4 = 256B bf16 row), 8 f32 accums,
// 16 edges in flight/wave. agg = dinv*(sum h'[src] + h'[node]); fused BN stats.
__global__ __launch_bounds__(512) void k_spmm1_csr(const int* __restrict__ rowptr,
        const int* __restrict__ col, const uint4* __restrict__ tbl,
        const float* __restrict__ dinv, uint4* __restrict__ agg4,
        float* __restrict__ accum, int n) {
    __shared__ float red[8][16][8];
    int t = threadIdx.x;
    int wid = t >> 6, lane = t & 63;
    int q = lane >> 4, g = lane & 15;
    int gw = blockIdx.x * 8 + wid;
    int nw = gridDim.x * 8;
    float sx[8], sq[8];
#pragma unroll
    for (int j = 0; j < 8; ++j) { sx[j] = 0.f; sq[j] = 0.f; }
    for (int node = gw; node < n; node += nw) {
        int beg = rowptr[node], end = rowptr[node + 1];
        float a[8];
#pragma unroll
        for (int j = 0; j < 8; ++j) a[j] = 0.f;
        if (q == 0) add8(tbl[(size_t)node * 16 + g], a);  // self-loop
        int p = beg;
        for (; p + 16 <= end; p += 16) {
            int c0 = col[p + q], c1 = col[p + 4 + q];
            int c2 = col[p + 8 + q], c3 = col[p + 12 + q];
            uint4 v0 = tbl[(size_t)c0 * 16 + g];
            uint4 v1 = tbl[(size_t)c1 * 16 + g];
            uint4 v2 = tbl[(size_t)c2 * 16 + g];
            uint4 v3 = tbl[(size_t)c3 * 16 + g];
            add8(v0, a); add8(v1, a); add8(v2, a); add8(v3, a);
        }
        if (p + 8 <= end) {
            int c0 = col[p + q], c1 = col[p + 4 + q];
            uint4 v0 = tbl[(size_t)c0 * 16 + g];
            uint4 v1 = tbl[(size_t)c1 * 16 + g];
            add8(v0, a); add8(v1, a);
            p += 8;
        }
        if (p < end) {
            int i0 = p + q, i1 = p + 4 + q;
            int c0 = col[i0 < end ? i0 : end - 1];
            int c1 = col[i1 < end ? i1 : end - 1];
            uint4 v0 = tbl[(size_t)c0 * 16 + g];
            uint4 v1 = tbl[(size_t)c1 * 16 + g];
            if (i0 < end) add8(v0, a);
            if (i1 < end) add8(v1, a);
        }
#pragma unroll
        for (int j = 0; j < 8; ++j) {
            a[j] += __shfl_xor(a[j], 16, 64);
            a[j] += __shfl_xor(a[j], 32, 64);
        }
        if (q == 0) {
            float di = dinv[node];
#pragma unroll
            for (int j = 0; j < 8; ++j) a[j] *= di;
            uint4 pk;
            pk.x = ((uint)f2bf(a[1]) << 16) | (uint)f2bf(a[0]);
            pk.y = ((uint)f2bf(a[3]) << 16) | (uint)f2bf(a[2]);
            pk.z = ((uint)f2bf(a[5]) << 16) | (uint)f2bf(a[4]);
            pk.w = ((uint)f2bf(a[7]) << 16) | (uint)f2bf(a[6]);
            agg4[(size_t)node * 16 + g] = pk;
#pragma unroll
            for (int j = 0; j < 8; ++j) {
                sx[j] += a[j];
                sq[j] = fmaf(a[j], a[j], sq[j]);
            }
        }
    }
    if (q == 0) {
#pragma unroll
        for (int j = 0; j < 8; ++j) red[wid][g][j] = sx[j];
    }
    __syncthreads();
    if (t < 128) {
        float v = 0.f;
        for (int w = 0; w < 8; ++w) v += red[w][t >> 3][t & 7];
        atomAddF(&accum[t], v);
    }
    __syncthreads();
    if (q == 0) {
#pragma unroll
        for (int j = 0; j < 8; ++j) red[wid][g][j] = sq[j];
    }
    __syncthreads();
    if (t < 128) {
        float v = 0.f;
        for (int w = 0; w < 8; ++w) v += red[w][t >> 3][t & 7];
        atomAddF(&accum[128 + t], v);
    }
}

// l_ext rows (192B): [ 64x f16 l*dinv | f16 s @128 ]; BN finalize fused.
__global__ __launch_bounds__(256) void k_gemm2_mfma(const ushort* __restrict__ agg_bf,
        const float* __restrict__ Wmu, const float* __restrict__ bmu,
        const float* __restrict__ accum, const float* __restrict__ gamma,
        const float* __restrict__ beta, const float* __restrict__ dinv,
        char* __restrict__ l_ext, float inv_n, int n, int nwt) {
    __shared__ ushort wf[4][4][64][8];  // 16KB
    __shared__ float scs[D_HID], shs[D_HID];
    int t = threadIdx.x;
    for (int i = t; i < 8192; i += 256) {
        int k = i >> 6, nn = i & 63;
        int kt = k >> 5, ct = nn >> 4;
        int lane = ((k >> 3) & 3) * 16 + (nn & 15);
        int j = k & 7;
        wf[kt][ct][lane][j] = f2bf(Wmu[i]);
    }
    for (int i = t; i < D_HID; i += 256) {  // fused bnfinal
        float mean = accum[i] * inv_n;
        float var = accum[D_HID + i] * inv_n - mean * mean;
        float sc = gamma[i] * rsqrtf(var + BN_EPS);
        scs[i] = sc;
        shs[i] = beta[i] - mean * sc;
    }
    __syncthreads();
    int wid = t >> 6, lane = t & 63;
    int lrow = lane & 15, lkg = lane >> 4;
    float bias[4];
#pragma unroll
    for (int ct = 0; ct < 4; ++ct) bias[ct] = bmu[ct * 16 + lrow];
    int stride = gridDim.x * 4;
    for (int wt = blockIdx.x * 4 + wid; wt < nwt; wt += stride) {
        size_t r0 = (size_t)wt * 16;
        int rr = (int)r0 + lrow;
        if (rr >= n) rr = n - 1;
        short8 ah[4], al[4];
#pragma unroll
        for (int kt = 0; kt < 4; ++kt) {
            const ushort* p = agg_bf + (size_t)rr * 128 + kt * 32 + lkg * 8;
            short8 raw = *(const short8*)p;
#pragma unroll
            for (int j = 0; j < 8; ++j) {
                int k = kt * 32 + lkg * 8 + j;
                float v = bf2f((ushort)raw[j]) * scs[k] + shs[k];
                v = v > 0.f ? v : SLOPE * v;
                ushort hb = f2bf(v);
                ah[kt][j] = (short)hb;
                al[kt][j] = (short)f2bf(v - bf2f(hb));
            }
        }
        f32x4 acc[4];
#pragma unroll
        for (int ct = 0; ct < 4; ++ct) {
            float bb = bias[ct];
            acc[ct][0] = bb; acc[ct][1] = bb; acc[ct][2] = bb; acc[ct][3] = bb;
        }
#pragma unroll
        for (int kt = 0; kt < 4; ++kt) {
#pragma unroll
            for (int ct = 0; ct < 4; ++ct) {
                short8 wh = *(const short8*)&wf[kt][ct][lane][0];
                acc[ct] = __builtin_amdgcn_mfma_f32_16x16x32_bf16(ah[kt], wh, acc[ct], 0, 0, 0);
                acc[ct] = __builtin_amdgcn_mfma_f32_16x16x32_bf16(al[kt], wh, acc[ct], 0, 0, 0);
            }
        }
#pragma unroll
        for (int j = 0; j < 4; ++j) {
            float ss = acc[0][j] * acc[0][j];
#pragma unroll
            for (int ct = 1; ct < 4; ++ct) ss = fmaf(acc[ct][j], acc[ct][j], ss);
            ss += __shfl_xor(ss, 1, 64);
            ss += __shfl_xor(ss, 2, 64);
            ss += __shfl_xor(ss, 4, 64);
            ss += __shfl_xor(ss, 8, 64);
            float srow = NSCALE / fmaxf(sqrtf(ss), 1e-12f);
            int row = (int)r0 + lkg * 4 + j;
            if (row < n) {
                float dr = dinv[row];
                char* base = l_ext + (size_t)row * LSTRIDE;
#pragma unroll
                for (int ct = 0; ct < 4; ++ct)
                    *(ushort*)(base + (ct * 16 + lrow) * 2) = f2h(acc[ct][j] * dr);
                if (lrow == 0) *(ushort*)(base + 128) = f2h(srow);
            }
        }
    }
}

// pull SpMM2: octet-per-edge (8 lanes x uint4 = 128B f16), packed half2 dual
// accum (mu & l*s), packed octet reduce, fused reparam.
__global__ __launch_bounds__(512) void k_spmm2_csr(const int* __restrict__ rowptr,
        const int* __restrict__ col, const char* __restrict__ lb,
        const float* __restrict__ dinv, const float* __restrict__ noise,
        float* __restrict__ mu, float* __restrict__ lsd, float* __restrict__ zeta,
        int n) {
    int node = blockIdx.x * 8 + ((int)threadIdx.x >> 6);
    if (node >= n) return;
    int lane = threadIdx.x & 63;
    int oct = lane >> 3, g = lane & 7;  // lane holds cols 8g..8g+7
    int beg = rowptr[node], end = rowptr[node + 1];
    __half2 hz = __float2half2_rn(0.f);
    __half2 am2[4] = {hz, hz, hz, hz}, al2[4] = {hz, hz, hz, hz};
    if (oct == 0) {  // self-loop
        const char* rb = lb + (size_t)node * LSTRIDE;
        uint4 v = *(const uint4*)(rb + g * 16);
        ushort sr = *(const ushort*)(rb + 128);
        __half2 s2 = __half2half2(*reinterpret_cast<const __half*>(&sr));
        pdacc8(v, s2, am2, al2);
    }
    int p = beg;
    for (; p + 16 <= end; p += 16) {
        int c0 = col[p + oct], c1 = col[p + 8 + oct];
        const char* r0 = lb + (size_t)c0 * LSTRIDE;
        const char* r1 = lb + (size_t)c1 * LSTRIDE;
        uint4 v0 = *(const uint4*)(r0 + g * 16);
        ushort sr0 = *(const ushort*)(r0 + 128);
        uint4 v1 = *(const uint4*)(r1 + g * 16);
        ushort sr1 = *(const ushort*)(r1 + 128);
        __half2 s20 = __half2half2(*reinterpret_cast<const __half*>(&sr0));
        __half2 s21 = __half2half2(*reinterpret_cast<const __half*>(&sr1));
        pdacc8(v0, s20, am2, al2);
        pdacc8(v1, s21, am2, al2);
    }
    if (p + 8 <= end) {
        int c0 = col[p + oct];
        const char* r0 = lb + (size_t)c0 * LSTRIDE;
        uint4 v0 = *(const uint4*)(r0 + g * 16);
        ushort sr0 = *(const ushort*)(r0 + 128);
        __half2 s20 = __half2half2(*reinterpret_cast<const __half*>(&sr0));
        pdacc8(v0, s20, am2, al2);
        p += 8;
    }
    if (p < end) {
        int i0 = p + oct;
        int c0 = col[i0 < end ? i0 : end - 1];
        const char* r0 = lb + (size_t)c0 * LSTRIDE;
        uint4 v0 = *(const uint4*)(r0 + g * 16);
        ushort sr0 = *(const ushort*)(r0 + 128);
        __half2 s20 = __half2half2(*reinterpret_cast<const __half*>(&sr0));
        if (i0 < end) pdacc8(v0, s20, am2, al2);
    }
    // packed reduce across octets
#pragma unroll
    for (int j = 0; j < 4; ++j) {
        am2[j] = __hadd2(am2[j], shfl_xor_h2(am2[j], 8));
        am2[j] = __hadd2(am2[j], shfl_xor_h2(am2[j], 16));
        am2[j] = __hadd2(am2[j], shfl_xor_h2(am2[j], 32));
        al2[j] = __hadd2(al2[j], shfl_xor_h2(al2[j], 8));
        al2[j] = __hadd2(al2[j], shfl_xor_h2(al2[j], 16));
        al2[j] = __hadd2(al2[j], shfl_xor_h2(al2[j], 32));
    }
    if (lane < 8) {
        float di = dinv[node];
        size_t idx = (size_t)node * 64 + lane * 8;
        float am[8], al[8];
#pragma unroll
        for (int j = 0; j < 4; ++j) {
            float2 fm = __half22float2(am2[j]);
            float2 fl = __half22float2(al2[j]);
            am[2 * j] = fm.x * di; am[2 * j + 1] = fm.y * di;
            al[2 * j] = fl.x * di; al[2 * j + 1] = fl.y * di;
        }
        f32x4 n0 = *(const f32x4*)(noise + idx);
        f32x4 n1 = *(const f32x4*)(noise + idx + 4);
        f32x4 m0, m1, l0, l1, z0, z1;
#pragma unroll
        for (int j = 0; j < 4; ++j) {
            m0[j] = am[j];     m1[j] = am[j + 4];
            l0[j] = al[j];     l1[j] = al[j + 4];
            z0[j] = m0[j] + n0[j] * expf(l0[j]);
            z1[j] = m1[j] + n1[j] * expf(l1[j]);
        }
        *(f32x4*)(mu + idx) = m0;   *(f32x4*)(mu + idx + 4) = m1;
        *(f32x4*)(lsd + idx) = l0;  *(f32x4*)(lsd + idx + 4) = l1;
        *(f32x4*)(zeta + idx) = z0; *(f32x4*)(zeta + idx + 4) = z1;
    }
}

extern "C" void kernel_launch(void* const* d_in, const int* in_sizes, int n_in,
                              void* d_out, int out_size, void* d_ws, size_t ws_size,
                              hipStream_t stream) {
    const float* x     = (const float*)d_in[0];
    const int*   esrc  = (const int*)d_in[1];
    const int*   edst  = (const int*)d_in[2];
    const float* W1    = (const float*)d_in[3];
    const float* b1    = (const float*)d_in[4];
    const float* gamma = (const float*)d_in[5];
    const float* beta  = (const float*)d_in[6];
    const float* Wmu   = (const float*)d_in[7];
    const float* bmu   = (const float*)d_in[8];
    const float* noise = (const float*)d_in[9];
    int N = in_sizes[0] / D_IN;
    int E = in_sizes[1];
    int B = (N + NB - 1) >> BSH;
    int nwt = (N + 15) / 16;
    int ntile = (E + T1 - 1) / T1;

    float* out  = (float*)d_out;
    float* mu   = out;
    float* lsd  = out + (size_t)N * D_OUT;
    float* zeta = out + 2 * (size_t)N * D_OUT;

    char* ws = (char*)d_ws;
    size_t off = 0;
    auto alloc = [&](size_t bytes) {
        void* p = ws + off;
        off += (bytes + 255) & ~(size_t)255;
        return p;
    };
    float* accum  = (float*)alloc(1024);
    int* bcnt     = (int*)alloc((size_t)B * 4);
    size_t zbytes = off;  // accum + bcnt zeroed
    int* bbase    = (int*)alloc(((size_t)B + 1) * 4);
    int* tailE    = (int*)alloc((size_t)B * 4);
    int* rowptr   = (int*)alloc(((size_t)N + 1) * 4);
    float* dinv   = (float*)alloc((size_t)N * 4);
    uint* ep      = (uint*)alloc((size_t)E * 4);
    int* col      = (int*)alloc((size_t)E * 4);
    ushort* h_bf  = (ushort*)alloc((size_t)N * D_HID * 2);
    uint4* agg4   = (uint4*)alloc((size_t)N * D_HID * 2);
    char* l_ext   = (char*)alloc((size_t)N * LSTRIDE);

    hipMemsetAsync(d_ws, 0, zbytes, stream);

    k_bhist<<<ntile, 256, 0, stream>>>(edst, bcnt, E, B);
    k_bscan<<<1, 512, 0, stream>>>(bcnt, bbase, tailE, B);
    k_part<<<ntile, 256, 0, stream>>>(esrc, edst, tailE, ep, E, B);
    k_csr<<<B, 256, 0, stream>>>(ep, bbase, rowptr, dinv, col, N, B);
    k_gemm1_mfma<<<512, 256, 0, stream>>>(x, W1, b1, dinv, h_bf, N, nwt);
    k_spmm1_csr<<<2048, 512, 0, stream>>>(rowptr, col, (const uint4*)h_bf, dinv, agg4, accum, N);
    k_gemm2_mfma<<<512, 256, 0, stream>>>((const ushort*)agg4, Wmu, bmu, accum,
                                          gamma, beta, dinv, l_ext, 1.0f / (float)N, N, nwt);
    k_spmm2_csr<<<(N + 7) / 8, 512, 0, stream>>>(rowptr, col, l_ext, dinv, noise, mu, lsd, zeta, N);
}

// Round 15
// 254.524 us; speedup vs baseline: 1.3964x; 1.0214x over previous
//
#include <hip/hip_runtime.h>
#include <hip/hip_bf16.h>
#include <hip/hip_fp16.h>
#include <math.h>

#define D_IN 128
#define D_HID 128
#define D_OUT 64
#define BN_EPS 1e-5f
#define SLOPE 0.01f
#define NSCALE 1.8f

#define BSH 8          // nodes per bucket = 256
#define NB 256
#define T1 4096        // edges per partition tile
#define COLCAP 8192

typedef __attribute__((ext_vector_type(8))) short short8;
typedef __attribute__((ext_vector_type(4))) float f32x4;

__device__ inline void atomAddF(float* p, float v) {
#if defined(__gfx90a__) || defined(__gfx942__) || defined(__gfx950__)
    unsafeAtomicAdd(p, v);
#else
    atomicAdd(p, v);
#endif
}

__device__ inline ushort f2bf(float f) {  // RNE
    union { float f; uint u; } v; v.f = f;
    uint r = v.u + 0x7fff + ((v.u >> 16) & 1);
    return (ushort)(r >> 16);
}
__device__ inline float bf2f(ushort b) {
    union { uint u; float f; } v; v.u = ((uint)b) << 16;
    return v.f;
}
__device__ inline float bflo(uint u) { return __uint_as_float(u << 16); }
__device__ inline float bfhi(uint u) { return __uint_as_float(u & 0xffff0000u); }
__device__ inline ushort f2h(float f) {
    __half h = __float2half_rn(f);
    return *reinterpret_cast<ushort*>(&h);
}
__device__ inline __half2 u2h2(uint u) { return *reinterpret_cast<__half2*>(&u); }
__device__ inline __half2 shfl_xor_h2(__half2 v, int m) {
    int iv = *reinterpret_cast<int*>(&v);
    int r = __shfl_xor(iv, m, 64);
    return *reinterpret_cast<__half2*>(&r);
}

// bf16 row add: 8 cols (uint4) into 8 f32 accumulators
__device__ inline void add8(uint4 v, float a[8]) {
    a[0] += bflo(v.x); a[1] += bfhi(v.x);
    a[2] += bflo(v.y); a[3] += bfhi(v.y);
    a[4] += bflo(v.z); a[5] += bfhi(v.z);
    a[6] += bflo(v.w); a[7] += bfhi(v.w);
}
// packed dual: am += v ; al += v*s2  (f16)
__device__ inline void pdacc8(uint4 v, __half2 s2, __half2 am[4], __half2 al[4]) {
    __half2 h0 = u2h2(v.x), h1 = u2h2(v.y), h2 = u2h2(v.z), h3 = u2h2(v.w);
    am[0] = __hadd2(am[0], h0); al[0] = __hfma2(h0, s2, al[0]);
    am[1] = __hadd2(am[1], h1); al[1] = __hfma2(h1, s2, al[1]);
    am[2] = __hadd2(am[2], h2); al[2] = __hfma2(h2, s2, al[2]);
    am[3] = __hadd2(am[3], h3); al[3] = __hfma2(h3, s2, al[3]);
}

// ---- bucket histogram (LDS-staged) -------------------------------------
__global__ __launch_bounds__(256) void k_bhist(const int* __restrict__ dst,
        int* __restrict__ bcnt, int E, int B) {
    __shared__ int h[512];
    for (int i = threadIdx.x; i < 512; i += 256) h[i] = 0;
    __syncthreads();
    int beg = blockIdx.x * T1;
    int end = min(beg + T1, E);
    for (int e = beg + threadIdx.x; e < end; e += 256)
        atomicAdd(&h[dst[e] >> BSH], 1);
    __syncthreads();
    for (int i = threadIdx.x; i < B; i += 256)
        if (h[i]) atomicAdd(&bcnt[i], h[i]);
}

// ---- bucket base scan (single block, B <= 512) -------------------------
__global__ __launch_bounds__(512) void k_bscan(const int* __restrict__ bcnt,
        int* __restrict__ bbase, int* __restrict__ tailE, int B) {
    __shared__ int sh[512];
    int t = threadIdx.x;
    int v = (t < B) ? bcnt[t] : 0;
    sh[t] = v;
    __syncthreads();
    for (int o = 1; o < 512; o <<= 1) {
        int u = (t >= o) ? sh[t - o] : 0;
        __syncthreads();
        sh[t] += u;
        __syncthreads();
    }
    int excl = sh[t] - v;
    if (t < B) { bbase[t] = excl; tailE[t] = excl; }
    if (t == B - 1) bbase[B] = excl + v;
}

// ---- partition edges into bucket regions; ep packed: src | dlocal<<24 --
__global__ __launch_bounds__(256) void k_part(const int* __restrict__ src,
        const int* __restrict__ dst, int* __restrict__ tailE,
        uint* __restrict__ ep, int E, int B) {
    __shared__ int h[512], off[512], gb[512], cur[512];
    __shared__ int ps[256];
    __shared__ int2 ro[T1];
    int tid = threadIdx.x;
    for (int i = tid; i < 512; i += 256) h[i] = 0;
    __syncthreads();
    int beg = blockIdx.x * T1;
    int cnt = min(T1, E - beg);
    int s[16], d[16];
#pragma unroll
    for (int k = 0; k < 16; ++k) {
        int e = beg + tid + k * 256;
        if (e < E) {
            s[k] = src[e]; d[k] = dst[e];
            atomicAdd(&h[d[k] >> BSH], 1);
        } else d[k] = -1;
    }
    __syncthreads();
    int pa = h[2 * tid], pb = h[2 * tid + 1];
    ps[tid] = pa + pb;
    __syncthreads();
    int vv = ps[tid];
    for (int o = 1; o < 256; o <<= 1) {
        int u = (tid >= o) ? ps[tid - o] : 0;
        __syncthreads();
        ps[tid] += u;
        __syncthreads();
    }
    int excl = ps[tid] - vv;
    off[2 * tid] = excl;       off[2 * tid + 1] = excl + pa;
    cur[2 * tid] = excl;       cur[2 * tid + 1] = excl + pa;
    if (2 * tid < B && pa > 0)      gb[2 * tid] = atomicAdd(&tailE[2 * tid], pa);
    if (2 * tid + 1 < B && pb > 0)  gb[2 * tid + 1] = atomicAdd(&tailE[2 * tid + 1], pb);
    __syncthreads();
#pragma unroll
    for (int k = 0; k < 16; ++k) {
        if (d[k] >= 0) {
            int b = d[k] >> BSH;
            int p = atomicAdd(&cur[b], 1);
            ro[p] = make_int2(s[k], d[k]);
        }
    }
    __syncthreads();
    for (int i = tid; i < cnt; i += 256) {
        int2 e = ro[i];
        int b = e.y >> BSH;
        ep[gb[b] + (i - off[b])] = (uint)e.x | ((uint)(e.y & (NB - 1)) << 24);
    }
}

// ---- per-bucket: deg/rowptr/dinv + CSR col build in LDS ----------------
__global__ __launch_bounds__(256) void k_csr(const uint* __restrict__ ep,
        const int* __restrict__ bbase, int* __restrict__ rowptr,
        float* __restrict__ dinv, int* __restrict__ col, int n, int B) {
    int b = blockIdx.x;
    int lo = b << BSH;
    int hi = min(lo + NB, n);
    int nn = hi - lo;
    int ebeg = bbase[b], eend = bbase[b + 1], cnt = eend - ebeg;
    __shared__ int h[NB], pfx[NB], cur[NB];
    __shared__ int colbuf[COLCAP];
    int tid = threadIdx.x;
    if (tid < NB) h[tid] = 0;
    __syncthreads();
    for (int i = tid; i < cnt; i += 256)
        atomicAdd(&h[ep[ebeg + i] >> 24], 1);
    __syncthreads();
    int v = (tid < nn) ? h[tid] : 0;
    pfx[tid] = v;
    __syncthreads();
    for (int o = 1; o < 256; o <<= 1) {
        int u = (tid >= o) ? pfx[tid - o] : 0;
        __syncthreads();
        pfx[tid] += u;
        __syncthreads();
    }
    int excl = pfx[tid] - v;
    if (tid < nn) {
        rowptr[lo + tid] = ebeg + excl;
        dinv[lo + tid] = rsqrtf((float)v + 1.0f);
        cur[tid] = excl;
    }
    if (b == B - 1 && tid == 0) rowptr[n] = eend;
    __syncthreads();
    if (cnt <= COLCAP) {
        for (int i = tid; i < cnt; i += 256) {
            uint e = ep[ebeg + i];
            int p = atomicAdd(&cur[e >> 24], 1);
            colbuf[p] = (int)(e & 0xFFFFFFu);
        }
        __syncthreads();
        for (int i = tid; i < cnt; i += 256) col[ebeg + i] = colbuf[i];
    } else {
        for (int i = tid; i < cnt; i += 256) {
            uint e = ep[ebeg + i];
            int p = atomicAdd(&cur[e >> 24], 1);
            col[ebeg + p] = (int)(e & 0xFFFFFFu);
        }
    }
}

// h' = bf16((x @ W1 + b1) * dinv[row]), row-major 128 cols (256B rows).
__global__ __launch_bounds__(256) void k_gemm1_mfma(const float* __restrict__ x,
        const float* __restrict__ W1, const float* __restrict__ b1,
        const float* __restrict__ dinv, ushort* __restrict__ h_bf, int n, int nwt) {
    __shared__ ushort wf[4][8][64][8];  // 32KB
    int t = threadIdx.x;
    for (int i = t; i < 16384; i += 256) {
        int k = i >> 7, nn = i & 127;
        int kt = k >> 5, ct = nn >> 4;
        int lane = ((k >> 3) & 3) * 16 + (nn & 15);
        int j = k & 7;
        wf[kt][ct][lane][j] = f2bf(W1[i]);
    }
    __syncthreads();
    int wid = t >> 6, lane = t & 63;
    int lrow = lane & 15, lkg = lane >> 4;
    float bias[8];
#pragma unroll
    for (int ct = 0; ct < 8; ++ct) bias[ct] = b1[ct * 16 + lrow];
    int stride = gridDim.x * 4;
    for (int wt = blockIdx.x * 4 + wid; wt < nwt; wt += stride) {
        size_t r0 = (size_t)wt * 16;
        int rr = (int)r0 + lrow;
        if (rr >= n) rr = n - 1;
        short8 ah[4], al[4];
#pragma unroll
        for (int kt = 0; kt < 4; ++kt) {
            const float* p = x + (size_t)rr * 128 + kt * 32 + lkg * 8;
            float va[8];
            *(f32x4*)&va[0] = *(const f32x4*)p;
            *(f32x4*)&va[4] = *(const f32x4*)(p + 4);
#pragma unroll
            for (int j = 0; j < 8; ++j) {
                ushort hb = f2bf(va[j]);
                ah[kt][j] = (short)hb;
                al[kt][j] = (short)f2bf(va[j] - bf2f(hb));
            }
        }
        f32x4 acc[8];
#pragma unroll
        for (int ct = 0; ct < 8; ++ct) {
            float bb = bias[ct];
            acc[ct][0] = bb; acc[ct][1] = bb; acc[ct][2] = bb; acc[ct][3] = bb;
        }
#pragma unroll
        for (int kt = 0; kt < 4; ++kt) {
#pragma unroll
            for (int ct = 0; ct < 8; ++ct) {
                short8 wh = *(const short8*)&wf[kt][ct][lane][0];
                acc[ct] = __builtin_amdgcn_mfma_f32_16x16x32_bf16(ah[kt], wh, acc[ct], 0, 0, 0);
                acc[ct] = __builtin_amdgcn_mfma_f32_16x16x32_bf16(al[kt], wh, acc[ct], 0, 0, 0);
            }
        }
#pragma unroll
        for (int j = 0; j < 4; ++j) {
            int row = (int)r0 + lkg * 4 + j;
            if (row < n) {
                float dr = dinv[row];
#pragma unroll
                for (int ct = 0; ct < 8; ++ct)
                    h_bf[(size_t)row * 128 + ct * 16 + lrow] = f2bf(acc[ct][j] * dr);
            }
        }
    }
}

// pull SpMM1: quarter-wave (16 lanes x uint4 = 256B bf16 row), 8 f32 accums,
// 16 edges in flight/wave. agg = dinv*(sum h'[src] + h'[node]); fused BN stats.
__global__ __launch_bounds__(512) void k_spmm1_csr(const int* __restrict__ rowptr,
        const int* __restrict__ col, const uint4* __restrict__ tbl,
        const float* __restrict__ dinv, uint4* __restrict__ agg4,
        float* __restrict__ accum, int n) {
    __shared__ float red[8][16][8];
    int t = threadIdx.x;
    int wid = t >> 6, lane = t & 63;
    int q = lane >> 4, g = lane & 15;
    int gw = blockIdx.x * 8 + wid;
    int nw = gridDim.x * 8;
    float sx[8], sq[8];
#pragma unroll
    for (int j = 0; j < 8; ++j) { sx[j] = 0.f; sq[j] = 0.f; }
    for (int node = gw; node < n; node += nw) {
        int beg = rowptr[node], end = rowptr[node + 1];
        float a[8];
#pragma unroll
        for (int j = 0; j < 8; ++j) a[j] = 0.f;
        if (q == 0) add8(tbl[(size_t)node * 16 + g], a);  // self-loop
        int p = beg;
        for (; p + 16 <= end; p += 16) {
            int c0 = col[p + q], c1 = col[p + 4 + q];
            int c2 = col[p + 8 + q], c3 = col[p + 12 + q];
            uint4 v0 = tbl[(size_t)c0 * 16 + g];
            uint4 v1 = tbl[(size_t)c1 * 16 + g];
            uint4 v2 = tbl[(size_t)c2 * 16 + g];
            uint4 v3 = tbl[(size_t)c3 * 16 + g];
            add8(v0, a); add8(v1, a); add8(v2, a); add8(v3, a);
        }
        if (p + 8 <= end) {
            int c0 = col[p + q], c1 = col[p + 4 + q];
            uint4 v0 = tbl[(size_t)c0 * 16 + g];
            uint4 v1 = tbl[(size_t)c1 * 16 + g];
            add8(v0, a); add8(v1, a);
            p += 8;
        }
        if (p < end) {
            int i0 = p + q, i1 = p + 4 + q;
            int c0 = col[i0 < end ? i0 : end - 1];
            int c1 = col[i1 < end ? i1 : end - 1];
            uint4 v0 = tbl[(size_t)c0 * 16 + g];
            uint4 v1 = tbl[(size_t)c1 * 16 + g];
            if (i0 < end) add8(v0, a);
            if (i1 < end) add8(v1, a);
        }
#pragma unroll
        for (int j = 0; j < 8; ++j) {
            a[j] += __shfl_xor(a[j], 16, 64);
            a[j] += __shfl_xor(a[j], 32, 64);
        }
        if (q == 0) {
            float di = dinv[node];
#pragma unroll
            for (int j = 0; j < 8; ++j) a[j] *= di;
            uint4 pk;
            pk.x = ((uint)f2bf(a[1]) << 16) | (uint)f2bf(a[0]);
            pk.y = ((uint)f2bf(a[3]) << 16) | (uint)f2bf(a[2]);
            pk.z = ((uint)f2bf(a[5]) << 16) | (uint)f2bf(a[4]);
            pk.w = ((uint)f2bf(a[7]) << 16) | (uint)f2bf(a[6]);
            agg4[(size_t)node * 16 + g] = pk;
#pragma unroll
            for (int j = 0; j < 8; ++j) {
                sx[j] += a[j];
                sq[j] = fmaf(a[j], a[j], sq[j]);
            }
        }
    }
    if (q == 0) {
#pragma unroll
        for (int j = 0; j < 8; ++j) red[wid][g][j] = sx[j];
    }
    __syncthreads();
    if (t < 128) {
        float v = 0.f;
        for (int w = 0; w < 8; ++w) v += red[w][t >> 3][t & 7];
        atomAddF(&accum[t], v);
    }
    __syncthreads();
    if (q == 0) {
#pragma unroll
        for (int j = 0; j < 8; ++j) red[wid][g][j] = sq[j];
    }
    __syncthreads();
    if (t < 128) {
        float v = 0.f;
        for (int w = 0; w < 8; ++w) v += red[w][t >> 3][t & 7];
        atomAddF(&accum[128 + t], v);
    }
}

// l16 rows (128B): 64x f16 l*dinv ; sOut: f32 per node. BN finalize fused.
__global__ __launch_bounds__(256) void k_gemm2_mfma(const ushort* __restrict__ agg_bf,
        const float* __restrict__ Wmu, const float* __restrict__ bmu,
        const float* __restrict__ accum, const float* __restrict__ gamma,
        const float* __restrict__ beta, const float* __restrict__ dinv,
        ushort* __restrict__ l16, float* __restrict__ sOut,
        float inv_n, int n, int nwt) {
    __shared__ ushort wf[4][4][64][8];  // 16KB
    __shared__ float scs[D_HID], shs[D_HID];
    int t = threadIdx.x;
    for (int i = t; i < 8192; i += 256) {
        int k = i >> 6, nn = i & 63;
        int kt = k >> 5, ct = nn >> 4;
        int lane = ((k >> 3) & 3) * 16 + (nn & 15);
        int j = k & 7;
        wf[kt][ct][lane][j] = f2bf(Wmu[i]);
    }
    for (int i = t; i < D_HID; i += 256) {  // fused bnfinal
        float mean = accum[i] * inv_n;
        float var = accum[D_HID + i] * inv_n - mean * mean;
        float sc = gamma[i] * rsqrtf(var + BN_EPS);
        scs[i] = sc;
        shs[i] = beta[i] - mean * sc;
    }
    __syncthreads();
    int wid = t >> 6, lane = t & 63;
    int lrow = lane & 15, lkg = lane >> 4;
    float bias[4];
#pragma unroll
    for (int ct = 0; ct < 4; ++ct) bias[ct] = bmu[ct * 16 + lrow];
    int stride = gridDim.x * 4;
    for (int wt = blockIdx.x * 4 + wid; wt < nwt; wt += stride) {
        size_t r0 = (size_t)wt * 16;
        int rr = (int)r0 + lrow;
        if (rr >= n) rr = n - 1;
        short8 ah[4], al[4];
#pragma unroll
        for (int kt = 0; kt < 4; ++kt) {
            const ushort* p = agg_bf + (size_t)rr * 128 + kt * 32 + lkg * 8;
            short8 raw = *(const short8*)p;
#pragma unroll
            for (int j = 0; j < 8; ++j) {
                int k = kt * 32 + lkg * 8 + j;
                float v = bf2f((ushort)raw[j]) * scs[k] + shs[k];
                v = v > 0.f ? v : SLOPE * v;
                ushort hb = f2bf(v);
                ah[kt][j] = (short)hb;
                al[kt][j] = (short)f2bf(v - bf2f(hb));
            }
        }
        f32x4 acc[4];
#pragma unroll
        for (int ct = 0; ct < 4; ++ct) {
            float bb = bias[ct];
            acc[ct][0] = bb; acc[ct][1] = bb; acc[ct][2] = bb; acc[ct][3] = bb;
        }
#pragma unroll
        for (int kt = 0; kt < 4; ++kt) {
#pragma unroll
            for (int ct = 0; ct < 4; ++ct) {
                short8 wh = *(const short8*)&wf[kt][ct][lane][0];
                acc[ct] = __builtin_amdgcn_mfma_f32_16x16x32_bf16(ah[kt], wh, acc[ct], 0, 0, 0);
                acc[ct] = __builtin_amdgcn_mfma_f32_16x16x32_bf16(al[kt], wh, acc[ct], 0, 0, 0);
            }
        }
#pragma unroll
        for (int j = 0; j < 4; ++j) {
            float ss = acc[0][j] * acc[0][j];
#pragma unroll
            for (int ct = 1; ct < 4; ++ct) ss = fmaf(acc[ct][j], acc[ct][j], ss);
            ss += __shfl_xor(ss, 1, 64);
            ss += __shfl_xor(ss, 2, 64);
            ss += __shfl_xor(ss, 4, 64);
            ss += __shfl_xor(ss, 8, 64);
            float srow = NSCALE / fmaxf(sqrtf(ss), 1e-12f);
            int row = (int)r0 + lkg * 4 + j;
            if (row < n) {
                float dr = dinv[row];
#pragma unroll
                for (int ct = 0; ct < 4; ++ct)
                    l16[(size_t)row * 64 + ct * 16 + lrow] = f2h(acc[ct][j] * dr);
                if (lrow == 0) sOut[row] = srow;   // lanes 0/16/32/48: one per lkg
            }
        }
    }
}

// pull SpMM2: octet-per-edge (8 lanes x uint4 = 128B f16 row) + L2-resident
// f32 s-gather, packed half2 dual accum, packed octet reduce, fused reparam.
__global__ __launch_bounds__(512) void k_spmm2_csr(const int* __restrict__ rowptr,
        const int* __restrict__ col, const uint4* __restrict__ l4,
        const float* __restrict__ sv, const float* __restrict__ dinv,
        const float* __restrict__ noise, float* __restrict__ mu,
        float* __restrict__ lsd, float* __restrict__ zeta, int n) {
    int node = blockIdx.x * 8 + ((int)threadIdx.x >> 6);
    if (node >= n) return;
    int lane = threadIdx.x & 63;
    int oct = lane >> 3, g = lane & 7;  // lane holds cols 8g..8g+7
    int beg = rowptr[node], end = rowptr[node + 1];
    __half2 hz = __float2half2_rn(0.f);
    __half2 am2[4] = {hz, hz, hz, hz}, al2[4] = {hz, hz, hz, hz};
    if (oct == 0) {  // self-loop (oct 0 only; summed across octets later)
        uint4 v = l4[(size_t)node * 8 + g];
        __half2 s2 = __float2half2_rn(sv[node]);
        pdacc8(v, s2, am2, al2);
    }
    int p = beg;
    for (; p + 16 <= end; p += 16) {
        int c0 = col[p + oct], c1 = col[p + 8 + oct];
        uint4 v0 = l4[(size_t)c0 * 8 + g];
        float s0 = sv[c0];
        uint4 v1 = l4[(size_t)c1 * 8 + g];
        float s1 = sv[c1];
        pdacc8(v0, __float2half2_rn(s0), am2, al2);
        pdacc8(v1, __float2half2_rn(s1), am2, al2);
    }
    if (p + 8 <= end) {
        int c0 = col[p + oct];
        uint4 v0 = l4[(size_t)c0 * 8 + g];
        float s0 = sv[c0];
        pdacc8(v0, __float2half2_rn(s0), am2, al2);
        p += 8;
    }
    if (p < end) {
        int i0 = p + oct;
        int c0 = col[i0 < end ? i0 : end - 1];
        uint4 v0 = l4[(size_t)c0 * 8 + g];
        float s0 = sv[c0];
        if (i0 < end) pdacc8(v0, __float2half2_rn(s0), am2, al2);
    }
    // packed reduce across octets
#pragma unroll
    for (int j = 0; j < 4; ++j) {
        am2[j] = __hadd2(am2[j], shfl_xor_h2(am2[j], 8));
        am2[j] = __hadd2(am2[j], shfl_xor_h2(am2[j], 16));
        am2[j] = __hadd2(am2[j], shfl_xor_h2(am2[j], 32));
        al2[j] = __hadd2(al2[j], shfl_xor_h2(al2[j], 8));
        al2[j] = __hadd2(al2[j], shfl_xor_h2(al2[j], 16));
        al2[j] = __hadd2(al2[j], shfl_xor_h2(al2[j], 32));
    }
    if (lane < 8) {
        float di = dinv[node];
        size_t idx = (size_t)node * 64 + lane * 8;
        float am[8], al[8];
#pragma unroll
        for (int j = 0; j < 4; ++j) {
            float2 fm = __half22float2(am2[j]);
            float2 fl = __half22float2(al2[j]);
            am[2 * j] = fm.x * di; am[2 * j + 1] = fm.y * di;
            al[2 * j] = fl.x * di; al[2 * j + 1] = fl.y * di;
        }
        f32x4 n0 = *(const f32x4*)(noise + idx);
        f32x4 n1 = *(const f32x4*)(noise + idx + 4);
        f32x4 m0, m1, l0, l1, z0, z1;
#pragma unroll
        for (int j = 0; j < 4; ++j) {
            m0[j] = am[j];     m1[j] = am[j + 4];
            l0[j] = al[j];     l1[j] = al[j + 4];
            z0[j] = m0[j] + n0[j] * expf(l0[j]);
            z1[j] = m1[j] + n1[j] * expf(l1[j]);
        }
        *(f32x4*)(mu + idx) = m0;   *(f32x4*)(mu + idx + 4) = m1;
        *(f32x4*)(lsd + idx) = l0;  *(f32x4*)(lsd + idx + 4) = l1;
        *(f32x4*)(zeta + idx) = z0; *(f32x4*)(zeta + idx + 4) = z1;
    }
}

extern "C" void kernel_launch(void* const* d_in, const int* in_sizes, int n_in,
                              void* d_out, int out_size, void* d_ws, size_t ws_size,
                              hipStream_t stream) {
    const float* x     = (const float*)d_in[0];
    const int*   esrc  = (const int*)d_in[1];
    const int*   edst  = (const int*)d_in[2];
    const float* W1    = (const float*)d_in[3];
    const float* b1    = (const float*)d_in[4];
    const float* gamma = (const float*)d_in[5];
    const float* beta  = (const float*)d_in[6];
    const float* Wmu   = (const float*)d_in[7];
    const float* bmu   = (const float*)d_in[8];
    const float* noise = (const float*)d_in[9];
    int N = in_sizes[0] / D_IN;
    int E = in_sizes[1];
    int B = (N + NB - 1) >> BSH;
    int nwt = (N + 15) / 16;
    int ntile = (E + T1 - 1) / T1;

    float* out  = (float*)d_out;
    float* mu   = out;
    float* lsd  = out + (size_t)N * D_OUT;
    float* zeta = out + 2 * (size_t)N * D_OUT;

    char* ws = (char*)d_ws;
    size_t off = 0;
    auto alloc = [&](size_t bytes) {
        void* p = ws + off;
        off += (bytes + 255) & ~(size_t)255;
        return p;
    };
    float* accum  = (float*)alloc(1024);
    int* bcnt     = (int*)alloc((size_t)B * 4);
    size_t zbytes = off;  // accum + bcnt zeroed
    int* bbase    = (int*)alloc(((size_t)B + 1) * 4);
    int* tailE    = (int*)alloc((size_t)B * 4);
    int* rowptr   = (int*)alloc(((size_t)N + 1) * 4);
    float* dinv   = (float*)alloc((size_t)N * 4);
    uint* ep      = (uint*)alloc((size_t)E * 4);
    int* col      = (int*)alloc((size_t)E * 4);
    ushort* h_bf  = (ushort*)alloc((size_t)N * D_HID * 2);
    uint4* agg4   = (uint4*)alloc((size_t)N * D_HID * 2);
    ushort* l16   = (ushort*)alloc((size_t)N * D_OUT * 2);
    float* sArr   = (float*)alloc((size_t)N * 4);

    hipMemsetAsync(d_ws, 0, zbytes, stream);

    k_bhist<<<ntile, 256, 0, stream>>>(edst, bcnt, E, B);
    k_bscan<<<1, 512, 0, stream>>>(bcnt, bbase, tailE, B);
    k_part<<<ntile, 256, 0, stream>>>(esrc, edst, tailE, ep, E, B);
    k_csr<<<B, 256, 0, stream>>>(ep, bbase, rowptr, dinv, col, N, B);
    k_gemm1_mfma<<<512, 256, 0, stream>>>(x, W1, b1, dinv, h_bf, N, nwt);
    k_spmm1_csr<<<1024, 512, 0, stream>>>(rowptr, col, (const uint4*)h_bf, dinv, agg4, accum, N);
    k_gemm2_mfma<<<512, 256, 0, stream>>>((const ushort*)agg4, Wmu, bmu, accum,
                                          gamma, beta, dinv, l16, sArr,
                                          1.0f / (float)N, N, nwt);
    k_spmm2_csr<<<(N + 7) / 8, 512, 0, stream>>>(rowptr, col, (const uint4*)l16,
                                                 sArr, dinv, noise, mu, lsd, zeta, N);
}